// Round 16
// baseline (487.623 us; speedup 1.0000x reference)
//
#include <hip/hip_runtime.h>
#include <hip/hip_bf16.h>
#include <math.h>

typedef __attribute__((ext_vector_type(8))) short bf8;
typedef __attribute__((ext_vector_type(4))) short bf4;
typedef __attribute__((ext_vector_type(4))) float f32x4;
typedef __attribute__((ext_vector_type(4))) unsigned short us4;

#define NTHR 512

// ---- LDS layout (bytes), MB=4 (64 rows). bf16 hi-only planes (2-term GEMMs),
// XOR-swizzled byte^=((row&7)<<4). 80 KB -> exactly 2 blocks/CU.
#define XHI 0u          // x hi  [64][256], row stride 512B (32 KB)
#define GHI 32768u      // rh hi [64][128], row stride 256B (16 KB)
#define H1HI 49152u     // h1 hi [64][128] (16 KB)
#define SHI 65536u      // h2 hi [64][128] (16 KB)
#define LDS_TOTAL 81920

// ---- workspace layout (bytes)
#define WS_LFRAG 0                      // 2 x 1KB L fragments (hi, lo)
#define WS_W1G   4096                   // 16nt*12ks*2*1024 = 393216
#define WS_W1C   (WS_W1G + 393216)      // 8nt*12ks*2*1024 = 196608
#define WS_W2G   (WS_W1C + 196608)      // 16nt*8ks*2*1024 = 262144
#define WS_W2C   (WS_W2G + 262144)      // 8nt*8ks*2*1024 = 131072

// exact-RNE software conversion (prep kernels only)
__device__ __forceinline__ unsigned short f2bf(float x) {
    unsigned u = __float_as_uint(x);
    unsigned r = (u + 0x7fffu + ((u >> 16) & 1u)) >> 16;
    return (unsigned short)r;
}
// native HW conversion (main kernel hot paths)
__device__ __forceinline__ unsigned short f2bf_n(float x) {
    union { __hip_bfloat16 b; unsigned short u; } t;
    t.b = __float2bfloat16(x);
    return t.u;
}
__device__ __forceinline__ float bf2f(unsigned short h) {
    return __uint_as_float(((unsigned)h) << 16);
}
__device__ __forceinline__ f32x4 mfma16(bf8 a, bf8 b, f32x4 c) {
    return __builtin_amdgcn_mfma_f32_16x16x32_bf16(a, b, c, 0, 0, 0);
}

// Aggregation MFMA: K=16 instruction when available (L-frag zeros k 4-7 anyway).
#if __has_builtin(__builtin_amdgcn_mfma_f32_16x16x16bf16_1k)
#define AGG16 1
typedef bf4 lfrag_t;
__device__ __forceinline__ f32x4 mfma_agg(bf4 a, bf4 b, f32x4 c) {
    return __builtin_amdgcn_mfma_f32_16x16x16bf16_1k(a, b, c, 0, 0, 0);
}
#else
#define AGG16 0
typedef bf8 lfrag_t;
__device__ __forceinline__ f32x4 mfma_agg(bf8 a, bf8 b, f32x4 c) {
    return __builtin_amdgcn_mfma_f32_16x16x32_bf16(a, b, c, 0, 0, 0);
}
#endif

// ---- 2-term GEMM: ah*(bh+bl) = bf16(activation) x exact-weight.
// XOR-swizzle folded to even/odd base pointers (verified R8):
// (ks*64 + lk*16)^sw == [(lk*16)^(sw&48)] + [ks*64 + s6 - 2*s6*(ks&1)], s6=sw&64.
// 4 M-tiles x 2 exclusive n-tiles (gate passes):
template<int KS, int RS>
__device__ __forceinline__ void gemm2nt_2t(const char* sm, unsigned hiO,
                                           const char* wp0, const char* wp1,
                                           unsigned l, f32x4 (&acc)[4][2]) {
    const unsigned lrow = l & 15u, lk = l >> 4;
    const unsigned sw = (lrow & 7u) << 4;
    const unsigned pp = (lk * 16u) ^ (sw & 48u);
    const unsigned s6 = sw & 64u;
    const char* eh = sm + hiO + lrow * (unsigned)RS + pp + s6;
    const char* oh = eh - 2 * (int)s6;
#pragma unroll 2
    for (int ks = 0; ks < KS; ++ks) {
        const char* ph = (ks & 1) ? oh : eh;
        const bf8 bh0 = *(const bf8*)(wp0 + (size_t)ks * 2048u);
        const bf8 bl0 = *(const bf8*)(wp0 + (size_t)ks * 2048u + 1024u);
        const bf8 bh1 = *(const bf8*)(wp1 + (size_t)ks * 2048u);
        const bf8 bl1 = *(const bf8*)(wp1 + (size_t)ks * 2048u + 1024u);
#pragma unroll
        for (int m = 0; m < 4; ++m) {
            const int off = ks * 64 + m * 16 * RS;
            const bf8 ah = *(const bf8*)(ph + off);
            acc[m][0] = mfma16(ah, bl0, mfma16(ah, bh0, acc[m][0]));
            acc[m][1] = mfma16(ah, bl1, mfma16(ah, bh1, acc[m][1]));
        }
    }
}

// 4 M-tiles x 1 n-tile (cand passes), 2-term:
template<int KS, int RS>
__device__ __forceinline__ void gemm1nt_2t(const char* sm, unsigned hiO,
                                           const char* wp, unsigned l, f32x4 (&acc)[4]) {
    const unsigned lrow = l & 15u, lk = l >> 4;
    const unsigned sw = (lrow & 7u) << 4;
    const unsigned pp = (lk * 16u) ^ (sw & 48u);
    const unsigned s6 = sw & 64u;
    const char* eh = sm + hiO + lrow * (unsigned)RS + pp + s6;
    const char* oh = eh - 2 * (int)s6;
#pragma unroll 2
    for (int ks = 0; ks < KS; ++ks) {
        const char* ph = (ks & 1) ? oh : eh;
        const bf8 bh = *(const bf8*)(wp + (size_t)ks * 2048u);
        const bf8 bl = *(const bf8*)(wp + (size_t)ks * 2048u + 1024u);
#pragma unroll
        for (int m = 0; m < 4; ++m) {
            const int off = ks * 64 + m * 16 * RS;
            const bf8 ah = *(const bf8*)(ph + off);
            acc[m] = mfma16(ah, bl, mfma16(ah, bh, acc[m]));
        }
    }
}

// Laplacian aggregation on a C-fragment: D = L @ pre  (split bf16, 3 agg-mfma)
__device__ __forceinline__ f32x4 agg3(lfrag_t Lhi, lfrag_t Llo, f32x4 p) {
    lfrag_t Bh, Bl;
#if !AGG16
    Bh = (bf8){0, 0, 0, 0, 0, 0, 0, 0};
    Bl = (bf8){0, 0, 0, 0, 0, 0, 0, 0};
#endif
#pragma unroll
    for (int q = 0; q < 4; ++q) {
        unsigned short h = f2bf_n(p[q]);
        Bh[q] = (short)h;
        Bl[q] = (short)f2bf_n(p[q] - bf2f(h));
    }
    f32x4 d = {0.f, 0.f, 0.f, 0.f};
    d = mfma_agg(Lhi, Bh, d);
    d = mfma_agg(Lhi, Bl, d);
    d = mfma_agg(Llo, Bh, d);
    return d;
}

// single-plane (hi) write for the 128-col planes (RS=256), swizzled
__device__ __forceinline__ void plane_wr_hi(char* sm, unsigned hiOff,
                                            unsigned row, unsigned col, float v) {
    unsigned off = row * 256u + ((col * 2u) ^ ((row & 7u) << 4));
    *(unsigned short*)(sm + hiOff + off) = f2bf_n(v);
}

__device__ __forceinline__ float fast_sigm(float x) {
    return __builtin_amdgcn_rcpf(1.0f + __expf(-x));
}
__device__ __forceinline__ float fast_tanh(float x) {
    float e = __expf(2.0f * fminf(x, 40.f));
    return (e - 1.0f) * __builtin_amdgcn_rcpf(e + 1.0f);
}

// feature loads for tile t (64 rows x 256 f32 = 4096 f32x4 / 512 thr = 8/thread)
__device__ __forceinline__ void stage_load(f32x4 (&v)[8], const float* __restrict__ feat,
                                           int b0, int t, int tid) {
#pragma unroll
    for (int p = 0; p < 8; ++p) {
        int e = tid + p * NTHR;
        int row = e >> 6, c4 = (e & 63) << 2;
        size_t gi = (((size_t)(b0 + (row >> 4)) * 5 + t) * 16 + (row & 15)) * 256 + c4;
        v[p] = __builtin_nontemporal_load((const f32x4*)(feat + gi));
    }
}
// hi-only bf16 staging
__device__ __forceinline__ void stage_store(char* sm, const f32x4 (&v)[8], int tid) {
#pragma unroll
    for (int p = 0; p < 8; ++p) {
        int e = tid + p * NTHR;
        int row = e >> 6, c4 = (e & 63) << 2;
        unsigned off = (unsigned)row * 512u + (((unsigned)c4 * 2u) ^ (((unsigned)row & 7u) << 4));
        us4 hi;
#pragma unroll
        for (int q = 0; q < 4; ++q) hi[q] = f2bf_n(v[p][q]);
        *(us4*)(sm + XHI + off) = hi;
    }
}

// ---------------- prep: Laplacian fragments ----------------
__global__ void tgcn_prep_L(const float* __restrict__ adj, char* __restrict__ ws) {
    __shared__ float d[16];
    __shared__ float Lm[16][16];
    int tid = threadIdx.x;
    if (tid < 16) {
        float rs = 1.0f;
        for (int j = 0; j < 16; ++j) rs += adj[tid * 16 + j];
        d[tid] = 1.0f / sqrtf(rs);
    }
    __syncthreads();
    if (tid < 256) {
        int i = tid >> 4, j = tid & 15;
        Lm[i][j] = (adj[j * 16 + i] + (i == j ? 1.0f : 0.0f)) * d[i] * d[j];
    }
    __syncthreads();
    if (tid < 128) {
        int h = tid >> 6, ll = tid & 63;
        int a = ll & 15, g = ll >> 4;
        bf8 f = {0, 0, 0, 0, 0, 0, 0, 0};
        for (int j = 0; j < 4; ++j) {
            float v = Lm[a][4 * g + j];
            unsigned short hi = f2bf(v);
            f[j] = (short)(h == 0 ? hi : f2bf(v - bf2f(hi)));
        }
        *(bf8*)(ws + WS_LFRAG + h * 1024 + ll * 16) = f;
    }
}

// ---------------- prep: weight fragment packing (hi/lo bf16) ----------------
__global__ void tgcn_prep_W(const float* __restrict__ w1g, const float* __restrict__ w1c,
                            const float* __restrict__ w2g, const float* __restrict__ w2c,
                            char* __restrict__ ws) {
    int gid = blockIdx.x * 256 + threadIdx.x;  // 480 frags * 64 lanes = 30720
    if (gid >= 30720) return;
    int fid = gid >> 6, l = gid & 63;
    const float* src; char* dst; int NK, N, nt, ks;
    if (fid < 192)      { src = w1g; dst = ws + WS_W1G; NK = 12; N = 256; nt = fid / 12; ks = fid % 12; }
    else if (fid < 288) { int f = fid - 192; src = w1c; dst = ws + WS_W1C; NK = 12; N = 128; nt = f / 12; ks = f % 12; }
    else if (fid < 416) { int f = fid - 288; src = w2g; dst = ws + WS_W2G; NK = 8;  N = 256; nt = f / 8;  ks = f % 8; }
    else                { int f = fid - 416; src = w2c; dst = ws + WS_W2C; NK = 8;  N = 128; nt = f / 8;  ks = f % 8; }
    int col = nt * 16 + (l & 15);
    int kbase = ks * 32 + (l >> 4) * 8;
    bf8 hi, lo;
#pragma unroll
    for (int j = 0; j < 8; ++j) {
        float v = src[(size_t)(kbase + j) * N + col];
        unsigned short h = f2bf(v);
        hi[j] = (short)h;
        lo[j] = (short)f2bf(v - bf2f(h));
    }
    char* base = dst + ((size_t)(nt * NK + ks) * 2048) + l * 16;
    *(bf8*)(base) = hi;
    *(bf8*)(base + 1024) = lo;
}

// ---------------- main fused kernel ----------------
// MB=4: 512 threads (8 waves), 64 rows (4 batches), 80 KB LDS -> 2 blocks/CU,
// 4 waves/SIMD at the proven 128-reg budget. Halves block count vs MB=2 ->
// halves L2 weight traffic (the largest pipe). vx prefetch overlaps cand1 only
// (issued after b2, stored after b3) so vx regs never coexist with gate acc.
__global__ __launch_bounds__(NTHR)
__attribute__((amdgpu_waves_per_eu(4, 4)))
void tgcn_main(
    const float* __restrict__ feat, const char* __restrict__ ws,
    const float* __restrict__ b1g, const float* __restrict__ b2g,
    const float* __restrict__ bng, const float* __restrict__ bnb,
    const float* __restrict__ bnm, const float* __restrict__ bnv,
    const float* __restrict__ fcw, const float* __restrict__ fcb,
    float* __restrict__ out) {
    extern __shared__ char sm[];
    const int tid = threadIdx.x;
    const int b0 = blockIdx.x * 4;
    const unsigned l = (unsigned)tid & 63u;
    const unsigned w = __builtin_amdgcn_readfirstlane((unsigned)tid >> 6);  // wave 0..7
    const unsigned lrow = l & 15u, lg = l >> 4;

    const lfrag_t Lhi = *(const lfrag_t*)(ws + WS_LFRAG + l * 16u);
    const lfrag_t Llo = *(const lfrag_t*)(ws + WS_LFRAG + 1024u + l * 16u);

    const float b1r = b1g[w * 16u + lrow];
    const float b1u = b1g[128u + w * 16u + lrow];
    const float b2r = b2g[w * 16u + lrow];
    const float b2u = b2g[128u + w * 16u + lrow];
    const unsigned col = w * 16u + lrow;   // this wave's H-column

    {
        f32x4 v[8];
        stage_load(v, feat, b0, 0, tid);
        stage_store(sm, v, tid);
    }
    __syncthreads();  // b1: X(0) ready (h planes never read at t=0)

    const char* wsW1G = ws + WS_W1G;
    const char* wsW1C = ws + WS_W1C;
    const char* wsW2G = ws + WS_W2G;
    const char* wsW2C = ws + WS_W2C;
    const f32x4 zf = {0.f, 0.f, 0.f, 0.f};

    float u1[4][4];                 // this wave's u-gate fragment [m][q]
    float h1v[4][4], h2v[4][4];     // register-resident h1/h2 column slice (fp32)
#pragma unroll
    for (int m = 0; m < 4; ++m)
#pragma unroll
        for (int q = 0; q < 4; ++q) { h1v[m][q] = 0.f; h2v[m][q] = 0.f; }

    for (int t = 0; t < 5; ++t) {
        // ---- gates1: [x | h1] @ w1g, K=384 (2-term). nt = {w, w+8}.
        {
            f32x4 acc[4][2] = {{zf, zf}, {zf, zf}, {zf, zf}, {zf, zf}};
            const char* wp0 = wsW1G + ((size_t)(w * 12u) * 2048u) + l * 16u;
            const char* wp1 = wsW1G + ((size_t)((w + 8u) * 12u) * 2048u) + l * 16u;
            __builtin_amdgcn_s_setprio(1);
            gemm2nt_2t<8, 512>(sm, XHI, wp0, wp1, l, acc);
            if (t > 0)
                gemm2nt_2t<4, 256>(sm, H1HI, wp0 + (size_t)8 * 2048u, wp1 + (size_t)8 * 2048u, l, acc);
            __builtin_amdgcn_s_setprio(0);
#pragma unroll
            for (int m = 0; m < 4; ++m) {
                f32x4 gr = agg3(Lhi, Llo, acc[m][0]);
                f32x4 gu = agg3(Lhi, Llo, acc[m][1]);
#pragma unroll
                for (int q = 0; q < 4; ++q) {
                    u1[m][q] = fast_sigm(gu[q] + b1u);
                    if (t > 0) {
                        float s = fast_sigm(gr[q] + b1r);
                        unsigned row = (unsigned)m * 16u + lg * 4u + (unsigned)q;
                        plane_wr_hi(sm, GHI, row, col, s * h1v[m][q]);
                    }
                }
            }
        }
        __syncthreads();  // b2: G(rh) ready

        // prefetch x(t+1): issued here so HBM latency hides under cand1's MFMA;
        // vx regs live only across cand1 (gate acc is dead here).
        f32x4 vx[8];
        if (t < 4) stage_load(vx, feat, b0, t + 1, tid);

        // ---- cand1: [x | rh] @ w1c, K=384 (2-term). nt = w; h1 update (regs + plane).
        {
            f32x4 acc[4] = {zf, zf, zf, zf};
            const char* wp = wsW1C + ((size_t)(w * 12u) * 2048u) + l * 16u;
            __builtin_amdgcn_s_setprio(1);
            gemm1nt_2t<8, 512>(sm, XHI, wp, l, acc);
            if (t > 0)
                gemm1nt_2t<4, 256>(sm, GHI, wp + (size_t)8 * 2048u, l, acc);
            __builtin_amdgcn_s_setprio(0);
#pragma unroll
            for (int m = 0; m < 4; ++m) {
                f32x4 c = agg3(Lhi, Llo, acc[m]);
#pragma unroll
                for (int q = 0; q < 4; ++q) {
                    float cv = fast_tanh(c[q]);
                    float u = u1[m][q];
                    float nh = u * h1v[m][q] + (1.0f - u) * cv;
                    h1v[m][q] = nh;
                    unsigned row = (unsigned)m * 16u + lg * 4u + (unsigned)q;
                    plane_wr_hi(sm, H1HI, row, col, nh);
                }
            }
        }
        __syncthreads();  // b3: h1 updated, X free

        // stage x(t+1) into X plane (X unused until next-t gates1)
        if (t < 4) stage_store(sm, vx, tid);

        // ---- gates2: [h1 | h2] @ w2g, K=256 (2-term). nt = {w, w+8}.
        {
            f32x4 acc[4][2] = {{zf, zf}, {zf, zf}, {zf, zf}, {zf, zf}};
            const char* wp0 = wsW2G + ((size_t)(w * 8u) * 2048u) + l * 16u;
            const char* wp1 = wsW2G + ((size_t)((w + 8u) * 8u) * 2048u) + l * 16u;
            __builtin_amdgcn_s_setprio(1);
            gemm2nt_2t<4, 256>(sm, H1HI, wp0, wp1, l, acc);
            if (t > 0)
                gemm2nt_2t<4, 256>(sm, SHI, wp0 + (size_t)4 * 2048u, wp1 + (size_t)4 * 2048u, l, acc);
            __builtin_amdgcn_s_setprio(0);
#pragma unroll
            for (int m = 0; m < 4; ++m) {
                f32x4 gr = agg3(Lhi, Llo, acc[m][0]);
                f32x4 gu = agg3(Lhi, Llo, acc[m][1]);
#pragma unroll
                for (int q = 0; q < 4; ++q) {
                    u1[m][q] = fast_sigm(gu[q] + b2u);
                    if (t > 0) {
                        float s = fast_sigm(gr[q] + b2r);
                        unsigned row = (unsigned)m * 16u + lg * 4u + (unsigned)q;
                        plane_wr_hi(sm, GHI, row, col, s * h2v[m][q]);
                    }
                }
            }
        }
        __syncthreads();  // b4: G(rh2) ready

        // ---- cand2: [h1 | rh2] @ w2c, K=256 (2-term). nt = w; h2 update.
        {
            f32x4 acc[4] = {zf, zf, zf, zf};
            const char* wp = wsW2C + ((size_t)(w * 8u) * 2048u) + l * 16u;
            __builtin_amdgcn_s_setprio(1);
            gemm1nt_2t<4, 256>(sm, H1HI, wp, l, acc);
            if (t > 0)
                gemm1nt_2t<4, 256>(sm, GHI, wp + (size_t)4 * 2048u, l, acc);
            __builtin_amdgcn_s_setprio(0);
#pragma unroll
            for (int m = 0; m < 4; ++m) {
                f32x4 c = agg3(Lhi, Llo, acc[m]);
#pragma unroll
                for (int q = 0; q < 4; ++q) {
                    float cv = fast_tanh(c[q]);
                    float u = u1[m][q];
                    float nh = u * h2v[m][q] + (1.0f - u) * cv;
                    h2v[m][q] = nh;
                    unsigned row = (unsigned)m * 16u + lg * 4u + (unsigned)q;
                    plane_wr_hi(sm, SHI, row, col, nh);
                }
            }
        }
        __syncthreads();  // b5: h2 updated, X(t+1) staged
    }

    // ---- head: BN -> ReLU -> FC(2048->2) from h2 (S hi plane, bf16)
    {
        int row = tid >> 3, cb = tid & 7;   // 64 rows x 8 col-blocks of 16
        int a = row & 15;
        unsigned c0 = (unsigned)cb * 16u;
        unsigned sw = ((unsigned)row & 7u) << 4;
        unsigned base = (unsigned)row * 256u;
        unsigned o0 = base + ((c0 * 2u) ^ sw);
        unsigned o1 = base + ((c0 * 2u + 16u) ^ sw);
        bf8 hA = *(const bf8*)(sm + SHI + o0);
        bf8 hB = *(const bf8*)(sm + SHI + o1);
        int k2 = a * 128 + (int)c0;
        float p0 = 0.f, p1 = 0.f;
#pragma unroll
        for (int j = 0; j < 16; ++j) {
            float v = bf2f((unsigned short)(j < 8 ? hA[j] : hB[j - 8]));
            int k = k2 + j;
            float x = bng[k] * (v - bnm[k]) * rsqrtf(bnv[k] + 1e-5f) + bnb[k];
            x = fmaxf(x, 0.f);
            p0 += x * fcw[2 * k];
            p1 += x * fcw[2 * k + 1];
        }
        p0 += __shfl_down(p0, 4, 8); p0 += __shfl_down(p0, 2, 8); p0 += __shfl_down(p0, 1, 8);
        p1 += __shfl_down(p1, 4, 8); p1 += __shfl_down(p1, 2, 8); p1 += __shfl_down(p1, 1, 8);
        if (cb == 0) {
            ((float*)(sm + GHI))[row * 2] = p0;
            ((float*)(sm + GHI))[row * 2 + 1] = p1;
        }
        __syncthreads();
        if (tid < 8) {
            int b = tid >> 1, o = tid & 1;
            float s = fcb[o];
#pragma unroll
            for (int aa = 0; aa < 16; ++aa) s += ((const float*)(sm + GHI))[(b * 16 + aa) * 2 + o];
            out[(size_t)(b0 + b) * 2 + o] = s;
        }
    }
}

extern "C" void kernel_launch(void* const* d_in, const int* in_sizes, int n_in,
                              void* d_out, int out_size, void* d_ws, size_t ws_size,
                              hipStream_t stream) {
    const float* feat = (const float*)d_in[0];
    const float* adj  = (const float*)d_in[1];
    const float* w1g  = (const float*)d_in[2];
    const float* b1g  = (const float*)d_in[3];
    const float* w1c  = (const float*)d_in[4];
    const float* w2g  = (const float*)d_in[5];
    const float* b2g  = (const float*)d_in[6];
    const float* w2c  = (const float*)d_in[7];
    const float* bng  = (const float*)d_in[8];
    const float* bnb  = (const float*)d_in[9];
    const float* bnm  = (const float*)d_in[10];
    const float* bnv  = (const float*)d_in[11];
    const float* fcw  = (const float*)d_in[12];
    const float* fcb  = (const float*)d_in[13];
    float* out = (float*)d_out;
    char* ws = (char*)d_ws;

    int B = in_sizes[0] / (5 * 16 * 256);  // 4096

    hipFuncSetAttribute((const void*)tgcn_main,
                        hipFuncAttributeMaxDynamicSharedMemorySize, LDS_TOTAL);

    tgcn_prep_L<<<1, 256, 0, stream>>>(adj, ws);
    tgcn_prep_W<<<120, 256, 0, stream>>>(w1g, w1c, w2g, w2c, ws);
    tgcn_main<<<B / 4, NTHR, LDS_TOTAL, stream>>>(feat, ws, b1g, b2g,
                                                  bng, bnb, bnm, bnv, fcw, fcb, out);
}

// Round 17
// 456.473 us; speedup vs baseline: 1.0682x; 1.0682x over previous
//
#include <hip/hip_runtime.h>
#include <hip/hip_bf16.h>
#include <math.h>

typedef __attribute__((ext_vector_type(8))) short bf8;
typedef __attribute__((ext_vector_type(4))) short bf4;
typedef __attribute__((ext_vector_type(4))) float f32x4;
typedef __attribute__((ext_vector_type(4))) unsigned short us4;

#define NTHR 512

// ---- LDS layout (bytes), MB=4 (64 rows). bf16 hi-only planes (2-term GEMMs),
// XOR-swizzled byte^=((row&7)<<4). 80 KB -> exactly 2 blocks/CU.
#define XHI 0u          // x hi  [64][256], row stride 512B (32 KB)
#define GHI 32768u      // rh hi [64][128], row stride 256B (16 KB)
#define H1HI 49152u     // h1 hi [64][128] (16 KB)
#define SHI 65536u      // h2 hi [64][128] (16 KB)
#define LDS_TOTAL 81920

// ---- workspace layout (bytes)
#define WS_LFRAG 0                      // 2 x 1KB L fragments (hi, lo)
#define WS_W1G   4096                   // 16nt*12ks*2*1024 = 393216
#define WS_W1C   (WS_W1G + 393216)      // 8nt*12ks*2*1024 = 196608
#define WS_W2G   (WS_W1C + 196608)      // 16nt*8ks*2*1024 = 262144
#define WS_W2C   (WS_W2G + 262144)      // 8nt*8ks*2*1024 = 131072

// exact-RNE software conversion (prep kernels only)
__device__ __forceinline__ unsigned short f2bf(float x) {
    unsigned u = __float_as_uint(x);
    unsigned r = (u + 0x7fffu + ((u >> 16) & 1u)) >> 16;
    return (unsigned short)r;
}
// native HW conversion (main kernel hot paths)
__device__ __forceinline__ unsigned short f2bf_n(float x) {
    union { __hip_bfloat16 b; unsigned short u; } t;
    t.b = __float2bfloat16(x);
    return t.u;
}
__device__ __forceinline__ float bf2f(unsigned short h) {
    return __uint_as_float(((unsigned)h) << 16);
}
__device__ __forceinline__ f32x4 mfma16(bf8 a, bf8 b, f32x4 c) {
    return __builtin_amdgcn_mfma_f32_16x16x32_bf16(a, b, c, 0, 0, 0);
}

// Aggregation MFMA: K=16 instruction when available (L-frag zeros k 4-7 anyway).
#if __has_builtin(__builtin_amdgcn_mfma_f32_16x16x16bf16_1k)
#define AGG16 1
typedef bf4 lfrag_t;
__device__ __forceinline__ f32x4 mfma_agg(bf4 a, bf4 b, f32x4 c) {
    return __builtin_amdgcn_mfma_f32_16x16x16bf16_1k(a, b, c, 0, 0, 0);
}
#else
#define AGG16 0
typedef bf8 lfrag_t;
__device__ __forceinline__ f32x4 mfma_agg(bf8 a, bf8 b, f32x4 c) {
    return __builtin_amdgcn_mfma_f32_16x16x32_bf16(a, b, c, 0, 0, 0);
}
#endif

// ---- 2-term GEMM: ah*(bh+bl) = bf16(activation) x exact-weight.
// XOR-swizzle folded to even/odd base pointers (verified R8).
// 4 M-tiles x 2 exclusive n-tiles (gate passes):
template<int KS, int RS>
__device__ __forceinline__ void gemm2nt_2t(const char* sm, unsigned hiO,
                                           const char* wp0, const char* wp1,
                                           unsigned l, f32x4 (&acc)[4][2]) {
    const unsigned lrow = l & 15u, lk = l >> 4;
    const unsigned sw = (lrow & 7u) << 4;
    const unsigned pp = (lk * 16u) ^ (sw & 48u);
    const unsigned s6 = sw & 64u;
    const char* eh = sm + hiO + lrow * (unsigned)RS + pp + s6;
    const char* oh = eh - 2 * (int)s6;
#pragma unroll 2
    for (int ks = 0; ks < KS; ++ks) {
        const char* ph = (ks & 1) ? oh : eh;
        const bf8 bh0 = *(const bf8*)(wp0 + (size_t)ks * 2048u);
        const bf8 bl0 = *(const bf8*)(wp0 + (size_t)ks * 2048u + 1024u);
        const bf8 bh1 = *(const bf8*)(wp1 + (size_t)ks * 2048u);
        const bf8 bl1 = *(const bf8*)(wp1 + (size_t)ks * 2048u + 1024u);
#pragma unroll
        for (int m = 0; m < 4; ++m) {
            const int off = ks * 64 + m * 16 * RS;
            const bf8 ah = *(const bf8*)(ph + off);
            acc[m][0] = mfma16(ah, bl0, mfma16(ah, bh0, acc[m][0]));
            acc[m][1] = mfma16(ah, bl1, mfma16(ah, bh1, acc[m][1]));
        }
    }
}

// 4 M-tiles x 1 n-tile (cand passes), 2-term:
template<int KS, int RS>
__device__ __forceinline__ void gemm1nt_2t(const char* sm, unsigned hiO,
                                           const char* wp, unsigned l, f32x4 (&acc)[4]) {
    const unsigned lrow = l & 15u, lk = l >> 4;
    const unsigned sw = (lrow & 7u) << 4;
    const unsigned pp = (lk * 16u) ^ (sw & 48u);
    const unsigned s6 = sw & 64u;
    const char* eh = sm + hiO + lrow * (unsigned)RS + pp + s6;
    const char* oh = eh - 2 * (int)s6;
#pragma unroll 2
    for (int ks = 0; ks < KS; ++ks) {
        const char* ph = (ks & 1) ? oh : eh;
        const bf8 bh = *(const bf8*)(wp + (size_t)ks * 2048u);
        const bf8 bl = *(const bf8*)(wp + (size_t)ks * 2048u + 1024u);
#pragma unroll
        for (int m = 0; m < 4; ++m) {
            const int off = ks * 64 + m * 16 * RS;
            const bf8 ah = *(const bf8*)(ph + off);
            acc[m] = mfma16(ah, bl, mfma16(ah, bh, acc[m]));
        }
    }
}

// Laplacian aggregation on a C-fragment: D = L @ pre  (split bf16, 3 agg-mfma)
__device__ __forceinline__ f32x4 agg3(lfrag_t Lhi, lfrag_t Llo, f32x4 p) {
    lfrag_t Bh, Bl;
#if !AGG16
    Bh = (bf8){0, 0, 0, 0, 0, 0, 0, 0};
    Bl = (bf8){0, 0, 0, 0, 0, 0, 0, 0};
#endif
#pragma unroll
    for (int q = 0; q < 4; ++q) {
        unsigned short h = f2bf_n(p[q]);
        Bh[q] = (short)h;
        Bl[q] = (short)f2bf_n(p[q] - bf2f(h));
    }
    f32x4 d = {0.f, 0.f, 0.f, 0.f};
    d = mfma_agg(Lhi, Bh, d);
    d = mfma_agg(Lhi, Bl, d);
    d = mfma_agg(Llo, Bh, d);
    return d;
}

// single-plane (hi) write for the 128-col planes (RS=256), swizzled
__device__ __forceinline__ void plane_wr_hi(char* sm, unsigned hiOff,
                                            unsigned row, unsigned col, float v) {
    unsigned off = row * 256u + ((col * 2u) ^ ((row & 7u) << 4));
    *(unsigned short*)(sm + hiOff + off) = f2bf_n(v);
}

__device__ __forceinline__ float fast_sigm(float x) {
    return __builtin_amdgcn_rcpf(1.0f + __expf(-x));
}
__device__ __forceinline__ float fast_tanh(float x) {
    float e = __expf(2.0f * fminf(x, 40.f));
    return (e - 1.0f) * __builtin_amdgcn_rcpf(e + 1.0f);
}

// half-tile feature load: 4 f32x4/thread, half = 0 or 1
__device__ __forceinline__ void stage_load_half(f32x4 (&v)[4], const float* __restrict__ feat,
                                                int b0, int t, int tid, int half) {
#pragma unroll
    for (int p = 0; p < 4; ++p) {
        int e = tid + (p + half * 4) * NTHR;
        int row = e >> 6, c4 = (e & 63) << 2;
        size_t gi = (((size_t)(b0 + (row >> 4)) * 5 + t) * 16 + (row & 15)) * 256 + c4;
        v[p] = __builtin_nontemporal_load((const f32x4*)(feat + gi));
    }
}
// hi-only bf16 staging of a half tile
__device__ __forceinline__ void stage_store_half(char* sm, const f32x4 (&v)[4], int tid, int half) {
#pragma unroll
    for (int p = 0; p < 4; ++p) {
        int e = tid + (p + half * 4) * NTHR;
        int row = e >> 6, c4 = (e & 63) << 2;
        unsigned off = (unsigned)row * 512u + (((unsigned)c4 * 2u) ^ (((unsigned)row & 7u) << 4));
        us4 hi;
#pragma unroll
        for (int q = 0; q < 4; ++q) hi[q] = f2bf_n(v[p][q]);
        *(us4*)(sm + XHI + off) = hi;
    }
}

// ---------------- prep: Laplacian fragments ----------------
__global__ void tgcn_prep_L(const float* __restrict__ adj, char* __restrict__ ws) {
    __shared__ float d[16];
    __shared__ float Lm[16][16];
    int tid = threadIdx.x;
    if (tid < 16) {
        float rs = 1.0f;
        for (int j = 0; j < 16; ++j) rs += adj[tid * 16 + j];
        d[tid] = 1.0f / sqrtf(rs);
    }
    __syncthreads();
    if (tid < 256) {
        int i = tid >> 4, j = tid & 15;
        Lm[i][j] = (adj[j * 16 + i] + (i == j ? 1.0f : 0.0f)) * d[i] * d[j];
    }
    __syncthreads();
    if (tid < 128) {
        int h = tid >> 6, ll = tid & 63;
        int a = ll & 15, g = ll >> 4;
        bf8 f = {0, 0, 0, 0, 0, 0, 0, 0};
        for (int j = 0; j < 4; ++j) {
            float v = Lm[a][4 * g + j];
            unsigned short hi = f2bf(v);
            f[j] = (short)(h == 0 ? hi : f2bf(v - bf2f(hi)));
        }
        *(bf8*)(ws + WS_LFRAG + h * 1024 + ll * 16) = f;
    }
}

// ---------------- prep: weight fragment packing (hi/lo bf16) ----------------
__global__ void tgcn_prep_W(const float* __restrict__ w1g, const float* __restrict__ w1c,
                            const float* __restrict__ w2g, const float* __restrict__ w2c,
                            char* __restrict__ ws) {
    int gid = blockIdx.x * 256 + threadIdx.x;  // 480 frags * 64 lanes = 30720
    if (gid >= 30720) return;
    int fid = gid >> 6, l = gid & 63;
    const float* src; char* dst; int NK, N, nt, ks;
    if (fid < 192)      { src = w1g; dst = ws + WS_W1G; NK = 12; N = 256; nt = fid / 12; ks = fid % 12; }
    else if (fid < 288) { int f = fid - 192; src = w1c; dst = ws + WS_W1C; NK = 12; N = 128; nt = f / 12; ks = f % 12; }
    else if (fid < 416) { int f = fid - 288; src = w2g; dst = ws + WS_W2G; NK = 8;  N = 256; nt = f / 8;  ks = f % 8; }
    else                { int f = fid - 416; src = w2c; dst = ws + WS_W2C; NK = 8;  N = 128; nt = f / 8;  ks = f % 8; }
    int col = nt * 16 + (l & 15);
    int kbase = ks * 32 + (l >> 4) * 8;
    bf8 hi, lo;
#pragma unroll
    for (int j = 0; j < 8; ++j) {
        float v = src[(size_t)(kbase + j) * N + col];
        unsigned short h = f2bf(v);
        hi[j] = (short)h;
        lo[j] = (short)f2bf(v - bf2f(h));
    }
    char* base = dst + ((size_t)(nt * NK + ks) * 2048) + l * 16;
    *(bf8*)(base) = hi;
    *(bf8*)(base + 1024) = lo;
}

// ---------------- main fused kernel ----------------
// MB=4: 512 threads (8 waves), 64 rows, 80 KB LDS -> 2 blocks/CU, 4 waves/SIMD.
// Halves block count vs MB=2 -> halves L2 weight traffic (largest pipe).
// Split x-prefetch: first half (vx[4], 16 regs) overlaps cand1; second half is
// loaded+stored serially after b3 (covered by the co-resident block). Keeps peak
// register state ~105 < 128 (R16's vx[8] spilled 344 MB).
__global__ __launch_bounds__(NTHR)
__attribute__((amdgpu_waves_per_eu(4, 4)))
void tgcn_main(
    const float* __restrict__ feat, const char* __restrict__ ws,
    const float* __restrict__ b1g, const float* __restrict__ b2g,
    const float* __restrict__ bng, const float* __restrict__ bnb,
    const float* __restrict__ bnm, const float* __restrict__ bnv,
    const float* __restrict__ fcw, const float* __restrict__ fcb,
    float* __restrict__ out) {
    extern __shared__ char sm[];
    const int tid = threadIdx.x;
    const int b0 = blockIdx.x * 4;
    const unsigned l = (unsigned)tid & 63u;
    const unsigned w = __builtin_amdgcn_readfirstlane((unsigned)tid >> 6);  // wave 0..7
    const unsigned lrow = l & 15u, lg = l >> 4;

    const lfrag_t Lhi = *(const lfrag_t*)(ws + WS_LFRAG + l * 16u);
    const lfrag_t Llo = *(const lfrag_t*)(ws + WS_LFRAG + 1024u + l * 16u);

    const float b1r = b1g[w * 16u + lrow];
    const float b1u = b1g[128u + w * 16u + lrow];
    const float b2r = b2g[w * 16u + lrow];
    const float b2u = b2g[128u + w * 16u + lrow];
    const unsigned col = w * 16u + lrow;   // this wave's H-column

    {
        f32x4 v[4];
        stage_load_half(v, feat, b0, 0, tid, 0);
        stage_store_half(sm, v, tid, 0);
        stage_load_half(v, feat, b0, 0, tid, 1);
        stage_store_half(sm, v, tid, 1);
    }
    __syncthreads();  // b1: X(0) ready (h planes never read at t=0)

    const char* wsW1G = ws + WS_W1G;
    const char* wsW1C = ws + WS_W1C;
    const char* wsW2G = ws + WS_W2G;
    const char* wsW2C = ws + WS_W2C;
    const f32x4 zf = {0.f, 0.f, 0.f, 0.f};

    float u1[4][4];                 // this wave's u-gate fragment [m][q]
    float h1v[4][4], h2v[4][4];     // register-resident h1/h2 column slice (fp32)
#pragma unroll
    for (int m = 0; m < 4; ++m)
#pragma unroll
        for (int q = 0; q < 4; ++q) { h1v[m][q] = 0.f; h2v[m][q] = 0.f; }

    for (int t = 0; t < 5; ++t) {
        // ---- gates1: [x | h1] @ w1g, K=384 (2-term). nt = {w, w+8}.
        {
            f32x4 acc[4][2] = {{zf, zf}, {zf, zf}, {zf, zf}, {zf, zf}};
            const char* wp0 = wsW1G + ((size_t)(w * 12u) * 2048u) + l * 16u;
            const char* wp1 = wsW1G + ((size_t)((w + 8u) * 12u) * 2048u) + l * 16u;
            __builtin_amdgcn_s_setprio(1);
            gemm2nt_2t<8, 512>(sm, XHI, wp0, wp1, l, acc);
            if (t > 0)
                gemm2nt_2t<4, 256>(sm, H1HI, wp0 + (size_t)8 * 2048u, wp1 + (size_t)8 * 2048u, l, acc);
            __builtin_amdgcn_s_setprio(0);
#pragma unroll
            for (int m = 0; m < 4; ++m) {
                f32x4 gr = agg3(Lhi, Llo, acc[m][0]);
                f32x4 gu = agg3(Lhi, Llo, acc[m][1]);
#pragma unroll
                for (int q = 0; q < 4; ++q) {
                    u1[m][q] = fast_sigm(gu[q] + b1u);
                    if (t > 0) {
                        float s = fast_sigm(gr[q] + b1r);
                        unsigned row = (unsigned)m * 16u + lg * 4u + (unsigned)q;
                        plane_wr_hi(sm, GHI, row, col, s * h1v[m][q]);
                    }
                }
            }
        }
        __syncthreads();  // b2: G(rh) ready

        // first-half x(t+1) prefetch: HBM latency hides under cand1's MFMA
        f32x4 vx[4];
        if (t < 4) stage_load_half(vx, feat, b0, t + 1, tid, 0);

        // ---- cand1: [x | rh] @ w1c, K=384 (2-term). nt = w; h1 update (regs + plane).
        {
            f32x4 acc[4] = {zf, zf, zf, zf};
            const char* wp = wsW1C + ((size_t)(w * 12u) * 2048u) + l * 16u;
            __builtin_amdgcn_s_setprio(1);
            gemm1nt_2t<8, 512>(sm, XHI, wp, l, acc);
            if (t > 0)
                gemm1nt_2t<4, 256>(sm, GHI, wp + (size_t)8 * 2048u, l, acc);
            __builtin_amdgcn_s_setprio(0);
#pragma unroll
            for (int m = 0; m < 4; ++m) {
                f32x4 c = agg3(Lhi, Llo, acc[m]);
#pragma unroll
                for (int q = 0; q < 4; ++q) {
                    float cv = fast_tanh(c[q]);
                    float u = u1[m][q];
                    float nh = u * h1v[m][q] + (1.0f - u) * cv;
                    h1v[m][q] = nh;
                    unsigned row = (unsigned)m * 16u + lg * 4u + (unsigned)q;
                    plane_wr_hi(sm, H1HI, row, col, nh);
                }
            }
        }
        __syncthreads();  // b3: h1 updated, X free

        // stage x(t+1): store prefetched half, then load+store second half
        if (t < 4) {
            stage_store_half(sm, vx, tid, 0);
            stage_load_half(vx, feat, b0, t + 1, tid, 1);
            stage_store_half(sm, vx, tid, 1);
        }

        // ---- gates2: [h1 | h2] @ w2g, K=256 (2-term). nt = {w, w+8}.
        {
            f32x4 acc[4][2] = {{zf, zf}, {zf, zf}, {zf, zf}, {zf, zf}};
            const char* wp0 = wsW2G + ((size_t)(w * 8u) * 2048u) + l * 16u;
            const char* wp1 = wsW2G + ((size_t)((w + 8u) * 8u) * 2048u) + l * 16u;
            __builtin_amdgcn_s_setprio(1);
            gemm2nt_2t<4, 256>(sm, H1HI, wp0, wp1, l, acc);
            if (t > 0)
                gemm2nt_2t<4, 256>(sm, SHI, wp0 + (size_t)4 * 2048u, wp1 + (size_t)4 * 2048u, l, acc);
            __builtin_amdgcn_s_setprio(0);
#pragma unroll
            for (int m = 0; m < 4; ++m) {
                f32x4 gr = agg3(Lhi, Llo, acc[m][0]);
                f32x4 gu = agg3(Lhi, Llo, acc[m][1]);
#pragma unroll
                for (int q = 0; q < 4; ++q) {
                    u1[m][q] = fast_sigm(gu[q] + b2u);
                    if (t > 0) {
                        float s = fast_sigm(gr[q] + b2r);
                        unsigned row = (unsigned)m * 16u + lg * 4u + (unsigned)q;
                        plane_wr_hi(sm, GHI, row, col, s * h2v[m][q]);
                    }
                }
            }
        }
        __syncthreads();  // b4: G(rh2) ready

        // ---- cand2: [h1 | rh2] @ w2c, K=256 (2-term). nt = w; h2 update.
        {
            f32x4 acc[4] = {zf, zf, zf, zf};
            const char* wp = wsW2C + ((size_t)(w * 8u) * 2048u) + l * 16u;
            __builtin_amdgcn_s_setprio(1);
            gemm1nt_2t<4, 256>(sm, H1HI, wp, l, acc);
            if (t > 0)
                gemm1nt_2t<4, 256>(sm, GHI, wp + (size_t)4 * 2048u, l, acc);
            __builtin_amdgcn_s_setprio(0);
#pragma unroll
            for (int m = 0; m < 4; ++m) {
                f32x4 c = agg3(Lhi, Llo, acc[m]);
#pragma unroll
                for (int q = 0; q < 4; ++q) {
                    float cv = fast_tanh(c[q]);
                    float u = u1[m][q];
                    float nh = u * h2v[m][q] + (1.0f - u) * cv;
                    h2v[m][q] = nh;
                    unsigned row = (unsigned)m * 16u + lg * 4u + (unsigned)q;
                    plane_wr_hi(sm, SHI, row, col, nh);
                }
            }
        }
        __syncthreads();  // b5: h2 updated, X(t+1) staged
    }

    // ---- head: BN -> ReLU -> FC(2048->2) from h2 (S hi plane, bf16)
    {
        int row = tid >> 3, cb = tid & 7;   // 64 rows x 8 col-blocks of 16
        int a = row & 15;
        unsigned c0 = (unsigned)cb * 16u;
        unsigned sw = ((unsigned)row & 7u) << 4;
        unsigned base = (unsigned)row * 256u;
        unsigned o0 = base + ((c0 * 2u) ^ sw);
        unsigned o1 = base + ((c0 * 2u + 16u) ^ sw);
        bf8 hA = *(const bf8*)(sm + SHI + o0);
        bf8 hB = *(const bf8*)(sm + SHI + o1);
        int k2 = a * 128 + (int)c0;
        float p0 = 0.f, p1 = 0.f;
#pragma unroll
        for (int j = 0; j < 16; ++j) {
            float v = bf2f((unsigned short)(j < 8 ? hA[j] : hB[j - 8]));
            int k = k2 + j;
            float x = bng[k] * (v - bnm[k]) * rsqrtf(bnv[k] + 1e-5f) + bnb[k];
            x = fmaxf(x, 0.f);
            p0 += x * fcw[2 * k];
            p1 += x * fcw[2 * k + 1];
        }
        p0 += __shfl_down(p0, 4, 8); p0 += __shfl_down(p0, 2, 8); p0 += __shfl_down(p0, 1, 8);
        p1 += __shfl_down(p1, 4, 8); p1 += __shfl_down(p1, 2, 8); p1 += __shfl_down(p1, 1, 8);
        if (cb == 0) {
            ((float*)(sm + GHI))[row * 2] = p0;
            ((float*)(sm + GHI))[row * 2 + 1] = p1;
        }
        __syncthreads();
        if (tid < 8) {
            int b = tid >> 1, o = tid & 1;
            float s = fcb[o];
#pragma unroll
            for (int aa = 0; aa < 16; ++aa) s += ((const float*)(sm + GHI))[(b * 16 + aa) * 2 + o];
            out[(size_t)(b0 + b) * 2 + o] = s;
        }
    }
}

extern "C" void kernel_launch(void* const* d_in, const int* in_sizes, int n_in,
                              void* d_out, int out_size, void* d_ws, size_t ws_size,
                              hipStream_t stream) {
    const float* feat = (const float*)d_in[0];
    const float* adj  = (const float*)d_in[1];
    const float* w1g  = (const float*)d_in[2];
    const float* b1g  = (const float*)d_in[3];
    const float* w1c  = (const float*)d_in[4];
    const float* w2g  = (const float*)d_in[5];
    const float* b2g  = (const float*)d_in[6];
    const float* w2c  = (const float*)d_in[7];
    const float* bng  = (const float*)d_in[8];
    const float* bnb  = (const float*)d_in[9];
    const float* bnm  = (const float*)d_in[10];
    const float* bnv  = (const float*)d_in[11];
    const float* fcw  = (const float*)d_in[12];
    const float* fcb  = (const float*)d_in[13];
    float* out = (float*)d_out;
    char* ws = (char*)d_ws;

    int B = in_sizes[0] / (5 * 16 * 256);  // 4096

    hipFuncSetAttribute((const void*)tgcn_main,
                        hipFuncAttributeMaxDynamicSharedMemorySize, LDS_TOTAL);

    tgcn_prep_L<<<1, 256, 0, stream>>>(adj, ws);
    tgcn_prep_W<<<120, 256, 0, stream>>>(w1g, w1c, w2g, w2c, ws);
    tgcn_main<<<B / 4, NTHR, LDS_TOTAL, stream>>>(feat, ws, b1g, b2g,
                                                  bng, bnb, bnm, bnv, fcw, fcb, out);
}

// Round 18
// 420.715 us; speedup vs baseline: 1.1590x; 1.0850x over previous
//
#include <hip/hip_runtime.h>
#include <hip/hip_bf16.h>
#include <math.h>

typedef __attribute__((ext_vector_type(8))) short bf8;
typedef __attribute__((ext_vector_type(4))) short bf4;
typedef __attribute__((ext_vector_type(4))) float f32x4;
typedef __attribute__((ext_vector_type(4))) unsigned short us4;

#define NTHR 512

// ---- LDS layout (bytes), MB=2 (32 rows). bf16 hi-only planes (2-term GEMMs),
// XOR-swizzled byte^=((row&7)<<4). 40 KB -> 2 blocks/CU (register-limited).
#define XHI 0u          // x hi  [32][256], row stride 512B (16 KB)
#define GHI 16384u      // rh hi [32][128], row stride 256B (8 KB)
#define H1HI 24576u     // h1 hi [32][128] (8 KB)
#define SHI 32768u      // h2 hi [32][128] (8 KB)
#define LDS_TOTAL 40960

// ---- workspace layout (bytes)
#define WS_LFRAG 0                      // 2 x 1KB L fragments (hi, lo)
#define WS_W1G   4096                   // 16nt*12ks*2*1024 = 393216
#define WS_W1C   (WS_W1G + 393216)      // 8nt*12ks*2*1024 = 196608
#define WS_W2G   (WS_W1C + 196608)      // 16nt*8ks*2*1024 = 262144
#define WS_W2C   (WS_W2G + 262144)      // 8nt*8ks*2*1024 = 131072

// exact-RNE software conversion (prep kernels only)
__device__ __forceinline__ unsigned short f2bf(float x) {
    unsigned u = __float_as_uint(x);
    unsigned r = (u + 0x7fffu + ((u >> 16) & 1u)) >> 16;
    return (unsigned short)r;
}
// native HW conversion (main kernel hot paths)
__device__ __forceinline__ unsigned short f2bf_n(float x) {
    union { __hip_bfloat16 b; unsigned short u; } t;
    t.b = __float2bfloat16(x);
    return t.u;
}
__device__ __forceinline__ float bf2f(unsigned short h) {
    return __uint_as_float(((unsigned)h) << 16);
}
__device__ __forceinline__ f32x4 mfma16(bf8 a, bf8 b, f32x4 c) {
    return __builtin_amdgcn_mfma_f32_16x16x32_bf16(a, b, c, 0, 0, 0);
}

// Aggregation MFMA: K=16 instruction when available (L-frag zeros k 4-7 anyway).
#if __has_builtin(__builtin_amdgcn_mfma_f32_16x16x16bf16_1k)
#define AGG16 1
typedef bf4 lfrag_t;
__device__ __forceinline__ f32x4 mfma_agg(bf4 a, bf4 b, f32x4 c) {
    return __builtin_amdgcn_mfma_f32_16x16x16bf16_1k(a, b, c, 0, 0, 0);
}
#else
#define AGG16 0
typedef bf8 lfrag_t;
__device__ __forceinline__ f32x4 mfma_agg(bf8 a, bf8 b, f32x4 c) {
    return __builtin_amdgcn_mfma_f32_16x16x32_bf16(a, b, c, 0, 0, 0);
}
#endif

// ---- 2-term GEMM: ah*(bh+bl) = bf16(activation) x exact-weight; err ~2^-9 rel
// on activations only (output absmax stays at/near the bf16 comparison floor).
// XOR-swizzle folded to even/odd base pointers (verified R8):
// (ks*64 + lk*16)^sw == [(lk*16)^(sw&48)] + [ks*64 + s6 - 2*s6*(ks&1)], s6=sw&64.
// 2 M-tiles x 2 exclusive n-tiles (gate passes):
template<int KS, int RS>
__device__ __forceinline__ void gemm2nt_2t(const char* sm, unsigned hiO,
                                           const char* wp0, const char* wp1,
                                           unsigned l, f32x4 (&acc)[2][2]) {
    const unsigned lrow = l & 15u, lk = l >> 4;
    const unsigned sw = (lrow & 7u) << 4;
    const unsigned pp = (lk * 16u) ^ (sw & 48u);
    const unsigned s6 = sw & 64u;
    const char* eh = sm + hiO + lrow * (unsigned)RS + pp + s6;
    const char* oh = eh - 2 * (int)s6;
#pragma unroll 2
    for (int ks = 0; ks < KS; ++ks) {
        const char* ph = (ks & 1) ? oh : eh;
        const bf8 bh0 = *(const bf8*)(wp0 + (size_t)ks * 2048u);
        const bf8 bl0 = *(const bf8*)(wp0 + (size_t)ks * 2048u + 1024u);
        const bf8 bh1 = *(const bf8*)(wp1 + (size_t)ks * 2048u);
        const bf8 bl1 = *(const bf8*)(wp1 + (size_t)ks * 2048u + 1024u);
#pragma unroll
        for (int m = 0; m < 2; ++m) {
            const int off = ks * 64 + m * 16 * RS;
            const bf8 ah = *(const bf8*)(ph + off);
            acc[m][0] = mfma16(ah, bl0, mfma16(ah, bh0, acc[m][0]));
            acc[m][1] = mfma16(ah, bl1, mfma16(ah, bh1, acc[m][1]));
        }
    }
}

// 2 M-tiles x 1 n-tile (cand passes), 2-term:
template<int KS, int RS>
__device__ __forceinline__ void gemm1nt_2t(const char* sm, unsigned hiO,
                                           const char* wp, unsigned l, f32x4 (&acc)[2]) {
    const unsigned lrow = l & 15u, lk = l >> 4;
    const unsigned sw = (lrow & 7u) << 4;
    const unsigned pp = (lk * 16u) ^ (sw & 48u);
    const unsigned s6 = sw & 64u;
    const char* eh = sm + hiO + lrow * (unsigned)RS + pp + s6;
    const char* oh = eh - 2 * (int)s6;
#pragma unroll 2
    for (int ks = 0; ks < KS; ++ks) {
        const char* ph = (ks & 1) ? oh : eh;
        const bf8 bh = *(const bf8*)(wp + (size_t)ks * 2048u);
        const bf8 bl = *(const bf8*)(wp + (size_t)ks * 2048u + 1024u);
#pragma unroll
        for (int m = 0; m < 2; ++m) {
            const int off = ks * 64 + m * 16 * RS;
            const bf8 ah = *(const bf8*)(ph + off);
            acc[m] = mfma16(ah, bl, mfma16(ah, bh, acc[m]));
        }
    }
}

// Laplacian aggregation on a C-fragment: D = L @ pre  (split bf16, 3 agg-mfma)
__device__ __forceinline__ f32x4 agg3(lfrag_t Lhi, lfrag_t Llo, f32x4 p) {
    lfrag_t Bh, Bl;
#if !AGG16
    Bh = (bf8){0, 0, 0, 0, 0, 0, 0, 0};
    Bl = (bf8){0, 0, 0, 0, 0, 0, 0, 0};
#endif
#pragma unroll
    for (int q = 0; q < 4; ++q) {
        unsigned short h = f2bf_n(p[q]);
        Bh[q] = (short)h;
        Bl[q] = (short)f2bf_n(p[q] - bf2f(h));
    }
    f32x4 d = {0.f, 0.f, 0.f, 0.f};
    d = mfma_agg(Lhi, Bh, d);
    d = mfma_agg(Lhi, Bl, d);
    d = mfma_agg(Llo, Bh, d);
    return d;
}

// single-plane (hi) write for the 128-col planes (RS=256), swizzled
__device__ __forceinline__ void plane_wr_hi(char* sm, unsigned hiOff,
                                            unsigned row, unsigned col, float v) {
    unsigned off = row * 256u + ((col * 2u) ^ ((row & 7u) << 4));
    *(unsigned short*)(sm + hiOff + off) = f2bf_n(v);
}

__device__ __forceinline__ float fast_sigm(float x) {
    return __builtin_amdgcn_rcpf(1.0f + __expf(-x));
}
__device__ __forceinline__ float fast_tanh(float x) {
    float e = __expf(2.0f * fminf(x, 40.f));
    return (e - 1.0f) * __builtin_amdgcn_rcpf(e + 1.0f);
}

// feature loads for tile t (32 rows x 256 f32 = 2048 f32x4 / 512 thr = 4/thread)
__device__ __forceinline__ void stage_load(f32x4 (&v)[4], const float* __restrict__ feat,
                                           int b0, int t, int tid) {
#pragma unroll
    for (int p = 0; p < 4; ++p) {
        int e = tid + p * NTHR;
        int row = e >> 6, c4 = (e & 63) << 2;
        size_t gi = (((size_t)(b0 + (row >> 4)) * 5 + t) * 16 + (row & 15)) * 256 + c4;
        v[p] = __builtin_nontemporal_load((const f32x4*)(feat + gi));
    }
}
// hi-only bf16 staging
__device__ __forceinline__ void stage_store(char* sm, const f32x4 (&v)[4], int tid) {
#pragma unroll
    for (int p = 0; p < 4; ++p) {
        int e = tid + p * NTHR;
        int row = e >> 6, c4 = (e & 63) << 2;
        unsigned off = (unsigned)row * 512u + (((unsigned)c4 * 2u) ^ (((unsigned)row & 7u) << 4));
        us4 hi;
#pragma unroll
        for (int q = 0; q < 4; ++q) hi[q] = f2bf_n(v[p][q]);
        *(us4*)(sm + XHI + off) = hi;
    }
}

// ---------------- prep: Laplacian fragments ----------------
__global__ void tgcn_prep_L(const float* __restrict__ adj, char* __restrict__ ws) {
    __shared__ float d[16];
    __shared__ float Lm[16][16];
    int tid = threadIdx.x;
    if (tid < 16) {
        float rs = 1.0f;
        for (int j = 0; j < 16; ++j) rs += adj[tid * 16 + j];
        d[tid] = 1.0f / sqrtf(rs);
    }
    __syncthreads();
    if (tid < 256) {
        int i = tid >> 4, j = tid & 15;
        Lm[i][j] = (adj[j * 16 + i] + (i == j ? 1.0f : 0.0f)) * d[i] * d[j];
    }
    __syncthreads();
    if (tid < 128) {
        int h = tid >> 6, ll = tid & 63;
        int a = ll & 15, g = ll >> 4;
        bf8 f = {0, 0, 0, 0, 0, 0, 0, 0};
        for (int j = 0; j < 4; ++j) {
            float v = Lm[a][4 * g + j];
            unsigned short hi = f2bf(v);
            f[j] = (short)(h == 0 ? hi : f2bf(v - bf2f(hi)));
        }
        *(bf8*)(ws + WS_LFRAG + h * 1024 + ll * 16) = f;
    }
}

// ---------------- prep: weight fragment packing (hi/lo bf16) ----------------
__global__ void tgcn_prep_W(const float* __restrict__ w1g, const float* __restrict__ w1c,
                            const float* __restrict__ w2g, const float* __restrict__ w2c,
                            char* __restrict__ ws) {
    int gid = blockIdx.x * 256 + threadIdx.x;  // 480 frags * 64 lanes = 30720
    if (gid >= 30720) return;
    int fid = gid >> 6, l = gid & 63;
    const float* src; char* dst; int NK, N, nt, ks;
    if (fid < 192)      { src = w1g; dst = ws + WS_W1G; NK = 12; N = 256; nt = fid / 12; ks = fid % 12; }
    else if (fid < 288) { int f = fid - 192; src = w1c; dst = ws + WS_W1C; NK = 12; N = 128; nt = f / 12; ks = f % 12; }
    else if (fid < 416) { int f = fid - 288; src = w2g; dst = ws + WS_W2G; NK = 8;  N = 256; nt = f / 8;  ks = f % 8; }
    else                { int f = fid - 416; src = w2c; dst = ws + WS_W2C; NK = 8;  N = 128; nt = f / 8;  ks = f % 8; }
    int col = nt * 16 + (l & 15);
    int kbase = ks * 32 + (l >> 4) * 8;
    bf8 hi, lo;
#pragma unroll
    for (int j = 0; j < 8; ++j) {
        float v = src[(size_t)(kbase + j) * N + col];
        unsigned short h = f2bf(v);
        hi[j] = (short)h;
        lo[j] = (short)f2bf(v - bf2f(h));
    }
    char* base = dst + ((size_t)(nt * NK + ks) * 2048) + l * 16;
    *(bf8*)(base) = hi;
    *(bf8*)(base + 1024) = lo;
}

// ---------------- main fused kernel ----------------
// MB=2: 512 threads (8 waves), 32 rows, 40 KB LDS, waves_per_eu(4,4) -> 2 blocks/CU
// at the proven spill-free 128-reg budget. R15 structure (the best measured point,
// 422 us) + hi-only S plane / bf16 head (R16/R17 measured absmax 9.77e-4, 2.9x
// under threshold). MB=4 variants regressed twice (spill or latency) - dead end.
__global__ __launch_bounds__(NTHR)
__attribute__((amdgpu_waves_per_eu(4, 4)))
void tgcn_main(
    const float* __restrict__ feat, const char* __restrict__ ws,
    const float* __restrict__ b1g, const float* __restrict__ b2g,
    const float* __restrict__ bng, const float* __restrict__ bnb,
    const float* __restrict__ bnm, const float* __restrict__ bnv,
    const float* __restrict__ fcw, const float* __restrict__ fcb,
    float* __restrict__ out) {
    extern __shared__ char sm[];
    const int tid = threadIdx.x;
    const int b0 = blockIdx.x * 2;
    const unsigned l = (unsigned)tid & 63u;
    const unsigned w = __builtin_amdgcn_readfirstlane((unsigned)tid >> 6);  // wave 0..7
    const unsigned lrow = l & 15u, lg = l >> 4;

    const lfrag_t Lhi = *(const lfrag_t*)(ws + WS_LFRAG + l * 16u);
    const lfrag_t Llo = *(const lfrag_t*)(ws + WS_LFRAG + 1024u + l * 16u);

    const float b1r = b1g[w * 16u + lrow];
    const float b1u = b1g[128u + w * 16u + lrow];
    const float b2r = b2g[w * 16u + lrow];
    const float b2u = b2g[128u + w * 16u + lrow];
    const unsigned col = w * 16u + lrow;   // this wave's H-column

    {
        f32x4 v[4];
        stage_load(v, feat, b0, 0, tid);
        stage_store(sm, v, tid);
    }
    __syncthreads();  // b1: X(0) ready (h planes never read at t=0)

    const char* wsW1G = ws + WS_W1G;
    const char* wsW1C = ws + WS_W1C;
    const char* wsW2G = ws + WS_W2G;
    const char* wsW2C = ws + WS_W2C;
    const f32x4 zf = {0.f, 0.f, 0.f, 0.f};

    float u1[2][4];                 // this wave's u-gate fragment [m][q]
    float h1v[2][4], h2v[2][4];     // register-resident h1/h2 column slice (fp32)
#pragma unroll
    for (int m = 0; m < 2; ++m)
#pragma unroll
        for (int q = 0; q < 4; ++q) { h1v[m][q] = 0.f; h2v[m][q] = 0.f; }

    for (int t = 0; t < 5; ++t) {
        // prefetch x(t+1) into registers; written to X plane after cand1 (b3)
        f32x4 vx[4];
        if (t < 4) stage_load(vx, feat, b0, t + 1, tid);

        // ---- gates1: [x | h1] @ w1g, K=384 (2-term). nt = {w, w+8}.
        {
            f32x4 acc[2][2] = {{zf, zf}, {zf, zf}};
            const char* wp0 = wsW1G + ((size_t)(w * 12u) * 2048u) + l * 16u;
            const char* wp1 = wsW1G + ((size_t)((w + 8u) * 12u) * 2048u) + l * 16u;
            __builtin_amdgcn_s_setprio(1);
            gemm2nt_2t<8, 512>(sm, XHI, wp0, wp1, l, acc);
            if (t > 0)
                gemm2nt_2t<4, 256>(sm, H1HI, wp0 + (size_t)8 * 2048u, wp1 + (size_t)8 * 2048u, l, acc);
            __builtin_amdgcn_s_setprio(0);
#pragma unroll
            for (int m = 0; m < 2; ++m) {
                f32x4 gr = agg3(Lhi, Llo, acc[m][0]);
                f32x4 gu = agg3(Lhi, Llo, acc[m][1]);
#pragma unroll
                for (int q = 0; q < 4; ++q) {
                    u1[m][q] = fast_sigm(gu[q] + b1u);
                    if (t > 0) {
                        float s = fast_sigm(gr[q] + b1r);
                        unsigned row = (unsigned)m * 16u + lg * 4u + (unsigned)q;
                        plane_wr_hi(sm, GHI, row, col, s * h1v[m][q]);
                    }
                }
            }
        }
        __syncthreads();  // b2: G(rh) ready

        // ---- cand1: [x | rh] @ w1c, K=384 (2-term). nt = w; h1 update (regs + plane).
        {
            f32x4 acc[2] = {zf, zf};
            const char* wp = wsW1C + ((size_t)(w * 12u) * 2048u) + l * 16u;
            __builtin_amdgcn_s_setprio(1);
            gemm1nt_2t<8, 512>(sm, XHI, wp, l, acc);
            if (t > 0)
                gemm1nt_2t<4, 256>(sm, GHI, wp + (size_t)8 * 2048u, l, acc);
            __builtin_amdgcn_s_setprio(0);
#pragma unroll
            for (int m = 0; m < 2; ++m) {
                f32x4 c = agg3(Lhi, Llo, acc[m]);
#pragma unroll
                for (int q = 0; q < 4; ++q) {
                    float cv = fast_tanh(c[q]);
                    float u = u1[m][q];
                    float nh = u * h1v[m][q] + (1.0f - u) * cv;
                    h1v[m][q] = nh;
                    unsigned row = (unsigned)m * 16u + lg * 4u + (unsigned)q;
                    plane_wr_hi(sm, H1HI, row, col, nh);
                }
            }
        }
        __syncthreads();  // b3: h1 updated, X free

        // stage x(t+1) into X plane (X unused until next-t gates1)
        if (t < 4) stage_store(sm, vx, tid);

        // ---- gates2: [h1 | h2] @ w2g, K=256 (2-term). nt = {w, w+8}.
        {
            f32x4 acc[2][2] = {{zf, zf}, {zf, zf}};
            const char* wp0 = wsW2G + ((size_t)(w * 8u) * 2048u) + l * 16u;
            const char* wp1 = wsW2G + ((size_t)((w + 8u) * 8u) * 2048u) + l * 16u;
            __builtin_amdgcn_s_setprio(1);
            gemm2nt_2t<4, 256>(sm, H1HI, wp0, wp1, l, acc);
            if (t > 0)
                gemm2nt_2t<4, 256>(sm, SHI, wp0 + (size_t)4 * 2048u, wp1 + (size_t)4 * 2048u, l, acc);
            __builtin_amdgcn_s_setprio(0);
#pragma unroll
            for (int m = 0; m < 2; ++m) {
                f32x4 gr = agg3(Lhi, Llo, acc[m][0]);
                f32x4 gu = agg3(Lhi, Llo, acc[m][1]);
#pragma unroll
                for (int q = 0; q < 4; ++q) {
                    u1[m][q] = fast_sigm(gu[q] + b2u);
                    if (t > 0) {
                        float s = fast_sigm(gr[q] + b2r);
                        unsigned row = (unsigned)m * 16u + lg * 4u + (unsigned)q;
                        plane_wr_hi(sm, GHI, row, col, s * h2v[m][q]);
                    }
                }
            }
        }
        __syncthreads();  // b4: G(rh2) ready

        // ---- cand2: [h1 | rh2] @ w2c, K=256 (2-term). nt = w; h2 update.
        {
            f32x4 acc[2] = {zf, zf};
            const char* wp = wsW2C + ((size_t)(w * 8u) * 2048u) + l * 16u;
            __builtin_amdgcn_s_setprio(1);
            gemm1nt_2t<4, 256>(sm, H1HI, wp, l, acc);
            if (t > 0)
                gemm1nt_2t<4, 256>(sm, GHI, wp + (size_t)4 * 2048u, l, acc);
            __builtin_amdgcn_s_setprio(0);
#pragma unroll
            for (int m = 0; m < 2; ++m) {
                f32x4 c = agg3(Lhi, Llo, acc[m]);
#pragma unroll
                for (int q = 0; q < 4; ++q) {
                    float cv = fast_tanh(c[q]);
                    float u = u1[m][q];
                    float nh = u * h2v[m][q] + (1.0f - u) * cv;
                    h2v[m][q] = nh;
                    unsigned row = (unsigned)m * 16u + lg * 4u + (unsigned)q;
                    plane_wr_hi(sm, SHI, row, col, nh);
                }
            }
        }
        __syncthreads();  // b5: h2 updated, X(t+1) staged
    }

    // ---- head: BN -> ReLU -> FC(2048->2) from h2 (S hi plane, bf16)
    {
        int row = tid >> 4, cb = tid & 15;   // 32 rows x 16 col-blocks of 8
        int a = row & 15;
        unsigned sw = ((unsigned)row & 7u) << 4;
        unsigned o0 = (unsigned)row * 256u + (((unsigned)cb * 16u) ^ sw);
        bf8 hA = *(const bf8*)(sm + SHI + o0);
        int k2 = a * 128 + cb * 8;
        float p0 = 0.f, p1 = 0.f;
#pragma unroll
        for (int j = 0; j < 8; ++j) {
            float v = bf2f((unsigned short)hA[j]);
            int k = k2 + j;
            float x = bng[k] * (v - bnm[k]) * rsqrtf(bnv[k] + 1e-5f) + bnb[k];
            x = fmaxf(x, 0.f);
            p0 += x * fcw[2 * k];
            p1 += x * fcw[2 * k + 1];
        }
        p0 += __shfl_down(p0, 8, 16); p0 += __shfl_down(p0, 4, 16);
        p0 += __shfl_down(p0, 2, 16); p0 += __shfl_down(p0, 1, 16);
        p1 += __shfl_down(p1, 8, 16); p1 += __shfl_down(p1, 4, 16);
        p1 += __shfl_down(p1, 2, 16); p1 += __shfl_down(p1, 1, 16);
        if (cb == 0) {
            ((float*)(sm + GHI))[row * 2] = p0;
            ((float*)(sm + GHI))[row * 2 + 1] = p1;
        }
        __syncthreads();
        if (tid < 4) {
            int b = tid >> 1, o = tid & 1;
            float s = fcb[o];
#pragma unroll
            for (int aa = 0; aa < 16; ++aa) s += ((const float*)(sm + GHI))[(b * 16 + aa) * 2 + o];
            out[(size_t)(b0 + b) * 2 + o] = s;
        }
    }
}

extern "C" void kernel_launch(void* const* d_in, const int* in_sizes, int n_in,
                              void* d_out, int out_size, void* d_ws, size_t ws_size,
                              hipStream_t stream) {
    const float* feat = (const float*)d_in[0];
    const float* adj  = (const float*)d_in[1];
    const float* w1g  = (const float*)d_in[2];
    const float* b1g  = (const float*)d_in[3];
    const float* w1c  = (const float*)d_in[4];
    const float* w2g  = (const float*)d_in[5];
    const float* b2g  = (const float*)d_in[6];
    const float* w2c  = (const float*)d_in[7];
    const float* bng  = (const float*)d_in[8];
    const float* bnb  = (const float*)d_in[9];
    const float* bnm  = (const float*)d_in[10];
    const float* bnv  = (const float*)d_in[11];
    const float* fcw  = (const float*)d_in[12];
    const float* fcb  = (const float*)d_in[13];
    float* out = (float*)d_out;
    char* ws = (char*)d_ws;

    int B = in_sizes[0] / (5 * 16 * 256);  // 4096

    hipFuncSetAttribute((const void*)tgcn_main,
                        hipFuncAttributeMaxDynamicSharedMemorySize, LDS_TOTAL);

    tgcn_prep_L<<<1, 256, 0, stream>>>(adj, ws);
    tgcn_prep_W<<<120, 256, 0, stream>>>(w1g, w1c, w2g, w2c, ws);
    tgcn_main<<<B / 2, NTHR, LDS_TOTAL, stream>>>(feat, ws, b1g, b2g,
                                                  bng, bnb, bnm, bnv, fcw, fcb, out);
}

// Round 19
// 414.919 us; speedup vs baseline: 1.1752x; 1.0140x over previous
//
#include <hip/hip_runtime.h>
#include <hip/hip_bf16.h>
#include <math.h>

typedef __attribute__((ext_vector_type(8))) short bf8;
typedef __attribute__((ext_vector_type(4))) short bf4;
typedef __attribute__((ext_vector_type(4))) float f32x4;
typedef __attribute__((ext_vector_type(4))) unsigned short us4;

#define NTHR 512

// ---- LDS layout (bytes), MB=2 (32 rows). bf16 hi-only planes (2-term GEMMs),
// XOR-swizzled byte^=((row&7)<<4). 40 KB -> 2 blocks/CU (register-limited).
#define XHI 0u          // x hi  [32][256], row stride 512B (16 KB)
#define GHI 16384u      // rh hi [32][128], row stride 256B (8 KB)
#define H1HI 24576u     // h1 hi [32][128] (8 KB)
#define SHI 32768u      // h2 hi [32][128] (8 KB)
#define LDS_TOTAL 40960

// ---- workspace layout (bytes)
#define WS_LFRAG 0                      // 2 x 1KB L fragments (hi, lo)
#define WS_W1G   4096                   // 16nt*12ks*2*1024 = 393216
#define WS_W1C   (WS_W1G + 393216)      // 8nt*12ks*2*1024 = 196608
#define WS_W2G   (WS_W1C + 196608)      // 16nt*8ks*2*1024 = 262144
#define WS_W2C   (WS_W2G + 262144)      // 8nt*8ks*2*1024 = 131072

// exact-RNE software conversion (prep kernels only)
__device__ __forceinline__ unsigned short f2bf(float x) {
    unsigned u = __float_as_uint(x);
    unsigned r = (u + 0x7fffu + ((u >> 16) & 1u)) >> 16;
    return (unsigned short)r;
}
// native HW conversion (main kernel hot paths)
__device__ __forceinline__ unsigned short f2bf_n(float x) {
    union { __hip_bfloat16 b; unsigned short u; } t;
    t.b = __float2bfloat16(x);
    return t.u;
}
__device__ __forceinline__ float bf2f(unsigned short h) {
    return __uint_as_float(((unsigned)h) << 16);
}
__device__ __forceinline__ f32x4 mfma16(bf8 a, bf8 b, f32x4 c) {
    return __builtin_amdgcn_mfma_f32_16x16x32_bf16(a, b, c, 0, 0, 0);
}

// Aggregation MFMA: K=16 instruction when available (L-frag zeros k 4-7 anyway).
#if __has_builtin(__builtin_amdgcn_mfma_f32_16x16x16bf16_1k)
#define AGG16 1
typedef bf4 lfrag_t;
__device__ __forceinline__ f32x4 mfma_agg(bf4 a, bf4 b, f32x4 c) {
    return __builtin_amdgcn_mfma_f32_16x16x16bf16_1k(a, b, c, 0, 0, 0);
}
#else
#define AGG16 0
typedef bf8 lfrag_t;
__device__ __forceinline__ f32x4 mfma_agg(bf8 a, bf8 b, f32x4 c) {
    return __builtin_amdgcn_mfma_f32_16x16x32_bf16(a, b, c, 0, 0, 0);
}
#endif

// ---- shared-A addressing (R8-verified XOR fold):
// (ks*64 + lk*16)^sw == [(lk*16)^(sw&48)] + [ks*64 + s6 - 2*s6*(ks&1)], s6=sw&64.

// FUSED segment: gates (2 n-tiles) + cand (1 n-tile) share each A-fragment.
// Per ks per m: 1 ds_read feeds 6 mfma (was 4+2 with a separate cand pass).
template<int KS, int RS>
__device__ __forceinline__ void gemm_fused(const char* sm, unsigned hiO,
                                           const char* wg0, const char* wg1,
                                           const char* wc,
                                           unsigned l, f32x4 (&accg)[2][2],
                                           f32x4 (&accc)[2]) {
    const unsigned lrow = l & 15u, lk = l >> 4;
    const unsigned sw = (lrow & 7u) << 4;
    const unsigned pp = (lk * 16u) ^ (sw & 48u);
    const unsigned s6 = sw & 64u;
    const char* eh = sm + hiO + lrow * (unsigned)RS + pp + s6;
    const char* oh = eh - 2 * (int)s6;
#pragma unroll 2
    for (int ks = 0; ks < KS; ++ks) {
        const char* ph = (ks & 1) ? oh : eh;
        const bf8 bh0 = *(const bf8*)(wg0 + (size_t)ks * 2048u);
        const bf8 bl0 = *(const bf8*)(wg0 + (size_t)ks * 2048u + 1024u);
        const bf8 bh1 = *(const bf8*)(wg1 + (size_t)ks * 2048u);
        const bf8 bl1 = *(const bf8*)(wg1 + (size_t)ks * 2048u + 1024u);
        const bf8 bhc = *(const bf8*)(wc + (size_t)ks * 2048u);
        const bf8 blc = *(const bf8*)(wc + (size_t)ks * 2048u + 1024u);
#pragma unroll
        for (int m = 0; m < 2; ++m) {
            const int off = ks * 64 + m * 16 * RS;
            const bf8 ah = *(const bf8*)(ph + off);
            accg[m][0] = mfma16(ah, bl0, mfma16(ah, bh0, accg[m][0]));
            accg[m][1] = mfma16(ah, bl1, mfma16(ah, bh1, accg[m][1]));
            accc[m]    = mfma16(ah, blc, mfma16(ah, bhc, accc[m]));
        }
    }
}

// gates-only segment, 2 M-tiles x 2 n-tiles (h-operand part):
template<int KS, int RS>
__device__ __forceinline__ void gemm2nt_2t(const char* sm, unsigned hiO,
                                           const char* wp0, const char* wp1,
                                           unsigned l, f32x4 (&acc)[2][2]) {
    const unsigned lrow = l & 15u, lk = l >> 4;
    const unsigned sw = (lrow & 7u) << 4;
    const unsigned pp = (lk * 16u) ^ (sw & 48u);
    const unsigned s6 = sw & 64u;
    const char* eh = sm + hiO + lrow * (unsigned)RS + pp + s6;
    const char* oh = eh - 2 * (int)s6;
#pragma unroll 2
    for (int ks = 0; ks < KS; ++ks) {
        const char* ph = (ks & 1) ? oh : eh;
        const bf8 bh0 = *(const bf8*)(wp0 + (size_t)ks * 2048u);
        const bf8 bl0 = *(const bf8*)(wp0 + (size_t)ks * 2048u + 1024u);
        const bf8 bh1 = *(const bf8*)(wp1 + (size_t)ks * 2048u);
        const bf8 bl1 = *(const bf8*)(wp1 + (size_t)ks * 2048u + 1024u);
#pragma unroll
        for (int m = 0; m < 2; ++m) {
            const int off = ks * 64 + m * 16 * RS;
            const bf8 ah = *(const bf8*)(ph + off);
            acc[m][0] = mfma16(ah, bl0, mfma16(ah, bh0, acc[m][0]));
            acc[m][1] = mfma16(ah, bl1, mfma16(ah, bh1, acc[m][1]));
        }
    }
}

// cand tail segment, 2 M-tiles x 1 n-tile (rh-operand part):
template<int KS, int RS>
__device__ __forceinline__ void gemm1nt_2t(const char* sm, unsigned hiO,
                                           const char* wp, unsigned l, f32x4 (&acc)[2]) {
    const unsigned lrow = l & 15u, lk = l >> 4;
    const unsigned sw = (lrow & 7u) << 4;
    const unsigned pp = (lk * 16u) ^ (sw & 48u);
    const unsigned s6 = sw & 64u;
    const char* eh = sm + hiO + lrow * (unsigned)RS + pp + s6;
    const char* oh = eh - 2 * (int)s6;
#pragma unroll 2
    for (int ks = 0; ks < KS; ++ks) {
        const char* ph = (ks & 1) ? oh : eh;
        const bf8 bh = *(const bf8*)(wp + (size_t)ks * 2048u);
        const bf8 bl = *(const bf8*)(wp + (size_t)ks * 2048u + 1024u);
#pragma unroll
        for (int m = 0; m < 2; ++m) {
            const int off = ks * 64 + m * 16 * RS;
            const bf8 ah = *(const bf8*)(ph + off);
            acc[m] = mfma16(ah, bl, mfma16(ah, bh, acc[m]));
        }
    }
}

// Laplacian aggregation on a C-fragment: D = L @ pre  (split bf16, 3 agg-mfma)
__device__ __forceinline__ f32x4 agg3(lfrag_t Lhi, lfrag_t Llo, f32x4 p) {
    lfrag_t Bh, Bl;
#if !AGG16
    Bh = (bf8){0, 0, 0, 0, 0, 0, 0, 0};
    Bl = (bf8){0, 0, 0, 0, 0, 0, 0, 0};
#endif
#pragma unroll
    for (int q = 0; q < 4; ++q) {
        unsigned short h = f2bf_n(p[q]);
        Bh[q] = (short)h;
        Bl[q] = (short)f2bf_n(p[q] - bf2f(h));
    }
    f32x4 d = {0.f, 0.f, 0.f, 0.f};
    d = mfma_agg(Lhi, Bh, d);
    d = mfma_agg(Lhi, Bl, d);
    d = mfma_agg(Llo, Bh, d);
    return d;
}

// single-plane (hi) write for the 128-col planes (RS=256), swizzled
__device__ __forceinline__ void plane_wr_hi(char* sm, unsigned hiOff,
                                            unsigned row, unsigned col, float v) {
    unsigned off = row * 256u + ((col * 2u) ^ ((row & 7u) << 4));
    *(unsigned short*)(sm + hiOff + off) = f2bf_n(v);
}

__device__ __forceinline__ float fast_sigm(float x) {
    return __builtin_amdgcn_rcpf(1.0f + __expf(-x));
}
__device__ __forceinline__ float fast_tanh(float x) {
    float e = __expf(2.0f * fminf(x, 40.f));
    return (e - 1.0f) * __builtin_amdgcn_rcpf(e + 1.0f);
}

// feature loads for tile t (32 rows x 256 f32 = 2048 f32x4 / 512 thr = 4/thread)
__device__ __forceinline__ void stage_load(f32x4 (&v)[4], const float* __restrict__ feat,
                                           int b0, int t, int tid) {
#pragma unroll
    for (int p = 0; p < 4; ++p) {
        int e = tid + p * NTHR;
        int row = e >> 6, c4 = (e & 63) << 2;
        size_t gi = (((size_t)(b0 + (row >> 4)) * 5 + t) * 16 + (row & 15)) * 256 + c4;
        v[p] = __builtin_nontemporal_load((const f32x4*)(feat + gi));
    }
}
// hi-only bf16 staging
__device__ __forceinline__ void stage_store(char* sm, const f32x4 (&v)[4], int tid) {
#pragma unroll
    for (int p = 0; p < 4; ++p) {
        int e = tid + p * NTHR;
        int row = e >> 6, c4 = (e & 63) << 2;
        unsigned off = (unsigned)row * 512u + (((unsigned)c4 * 2u) ^ (((unsigned)row & 7u) << 4));
        us4 hi;
#pragma unroll
        for (int q = 0; q < 4; ++q) hi[q] = f2bf_n(v[p][q]);
        *(us4*)(sm + XHI + off) = hi;
    }
}

// ---------------- prep: Laplacian fragments ----------------
__global__ void tgcn_prep_L(const float* __restrict__ adj, char* __restrict__ ws) {
    __shared__ float d[16];
    __shared__ float Lm[16][16];
    int tid = threadIdx.x;
    if (tid < 16) {
        float rs = 1.0f;
        for (int j = 0; j < 16; ++j) rs += adj[tid * 16 + j];
        d[tid] = 1.0f / sqrtf(rs);
    }
    __syncthreads();
    if (tid < 256) {
        int i = tid >> 4, j = tid & 15;
        Lm[i][j] = (adj[j * 16 + i] + (i == j ? 1.0f : 0.0f)) * d[i] * d[j];
    }
    __syncthreads();
    if (tid < 128) {
        int h = tid >> 6, ll = tid & 63;
        int a = ll & 15, g = ll >> 4;
        bf8 f = {0, 0, 0, 0, 0, 0, 0, 0};
        for (int j = 0; j < 4; ++j) {
            float v = Lm[a][4 * g + j];
            unsigned short hi = f2bf(v);
            f[j] = (short)(h == 0 ? hi : f2bf(v - bf2f(hi)));
        }
        *(bf8*)(ws + WS_LFRAG + h * 1024 + ll * 16) = f;
    }
}

// ---------------- prep: weight fragment packing (hi/lo bf16) ----------------
__global__ void tgcn_prep_W(const float* __restrict__ w1g, const float* __restrict__ w1c,
                            const float* __restrict__ w2g, const float* __restrict__ w2c,
                            char* __restrict__ ws) {
    int gid = blockIdx.x * 256 + threadIdx.x;  // 480 frags * 64 lanes = 30720
    if (gid >= 30720) return;
    int fid = gid >> 6, l = gid & 63;
    const float* src; char* dst; int NK, N, nt, ks;
    if (fid < 192)      { src = w1g; dst = ws + WS_W1G; NK = 12; N = 256; nt = fid / 12; ks = fid % 12; }
    else if (fid < 288) { int f = fid - 192; src = w1c; dst = ws + WS_W1C; NK = 12; N = 128; nt = f / 12; ks = f % 12; }
    else if (fid < 416) { int f = fid - 288; src = w2g; dst = ws + WS_W2G; NK = 8;  N = 256; nt = f / 8;  ks = f % 8; }
    else                { int f = fid - 416; src = w2c; dst = ws + WS_W2C; NK = 8;  N = 128; nt = f / 8;  ks = f % 8; }
    int col = nt * 16 + (l & 15);
    int kbase = ks * 32 + (l >> 4) * 8;
    bf8 hi, lo;
#pragma unroll
    for (int j = 0; j < 8; ++j) {
        float v = src[(size_t)(kbase + j) * N + col];
        unsigned short h = f2bf(v);
        hi[j] = (short)h;
        lo[j] = (short)f2bf(v - bf2f(h));
    }
    char* base = dst + ((size_t)(nt * NK + ks) * 2048) + l * 16;
    *(bf8*)(base) = hi;
    *(bf8*)(base + 1024) = lo;
}

// ---------------- main fused kernel ----------------
// MB=2: 512 threads (8 waves), 32 rows, 40 KB LDS, waves_per_eu(4,4) -> 2 blocks/CU.
// NEW (R19): cand GEMMs share the X / h1 A-fragments with the gate GEMMs in a
// fused phase (1 ds_read feeds 6 mfma); only the rh tail (4 ks) runs after the
// barrier. Cuts LDS reads 30% and shortens the cand critical path. Dataflow and
// barrier structure otherwise identical to R18 (420.7 us best).
__global__ __launch_bounds__(NTHR)
__attribute__((amdgpu_waves_per_eu(4, 4)))
void tgcn_main(
    const float* __restrict__ feat, const char* __restrict__ ws,
    const float* __restrict__ b1g, const float* __restrict__ b2g,
    const float* __restrict__ bng, const float* __restrict__ bnb,
    const float* __restrict__ bnm, const float* __restrict__ bnv,
    const float* __restrict__ fcw, const float* __restrict__ fcb,
    float* __restrict__ out) {
    extern __shared__ char sm[];
    const int tid = threadIdx.x;
    const int b0 = blockIdx.x * 2;
    const unsigned l = (unsigned)tid & 63u;
    const unsigned w = __builtin_amdgcn_readfirstlane((unsigned)tid >> 6);  // wave 0..7
    const unsigned lrow = l & 15u, lg = l >> 4;

    const lfrag_t Lhi = *(const lfrag_t*)(ws + WS_LFRAG + l * 16u);
    const lfrag_t Llo = *(const lfrag_t*)(ws + WS_LFRAG + 1024u + l * 16u);

    const float b1r = b1g[w * 16u + lrow];
    const float b1u = b1g[128u + w * 16u + lrow];
    const float b2r = b2g[w * 16u + lrow];
    const float b2u = b2g[128u + w * 16u + lrow];
    const unsigned col = w * 16u + lrow;   // this wave's H-column

    {
        f32x4 v[4];
        stage_load(v, feat, b0, 0, tid);
        stage_store(sm, v, tid);
    }
    __syncthreads();  // b1: X(0) ready (h planes never read at t=0)

    const char* wsW1G = ws + WS_W1G;
    const char* wsW1C = ws + WS_W1C;
    const char* wsW2G = ws + WS_W2G;
    const char* wsW2C = ws + WS_W2C;
    const f32x4 zf = {0.f, 0.f, 0.f, 0.f};

    float u1[2][4];                 // this wave's u-gate fragment [m][q]
    float h1v[2][4], h2v[2][4];     // register-resident h1/h2 column slice (fp32)
#pragma unroll
    for (int m = 0; m < 2; ++m)
#pragma unroll
        for (int q = 0; q < 4; ++q) { h1v[m][q] = 0.f; h2v[m][q] = 0.f; }

    for (int t = 0; t < 5; ++t) {
        const char* wp1g0 = wsW1G + ((size_t)(w * 12u) * 2048u) + l * 16u;
        const char* wp1g1 = wsW1G + ((size_t)((w + 8u) * 12u) * 2048u) + l * 16u;
        const char* wp1c  = wsW1C + ((size_t)(w * 12u) * 2048u) + l * 16u;

        // ---- phase 1: gates1 (full K) fused with cand1's X-part (ks 0..7).
        f32x4 accc1[2] = {zf, zf};
        {
            f32x4 acc[2][2] = {{zf, zf}, {zf, zf}};
            __builtin_amdgcn_s_setprio(1);
            gemm_fused<8, 512>(sm, XHI, wp1g0, wp1g1, wp1c, l, acc, accc1);
            if (t > 0)
                gemm2nt_2t<4, 256>(sm, H1HI, wp1g0 + (size_t)8 * 2048u, wp1g1 + (size_t)8 * 2048u, l, acc);
            __builtin_amdgcn_s_setprio(0);
#pragma unroll
            for (int m = 0; m < 2; ++m) {
                f32x4 gr = agg3(Lhi, Llo, acc[m][0]);
                f32x4 gu = agg3(Lhi, Llo, acc[m][1]);
#pragma unroll
                for (int q = 0; q < 4; ++q) {
                    u1[m][q] = fast_sigm(gu[q] + b1u);
                    if (t > 0) {
                        float s = fast_sigm(gr[q] + b1r);
                        unsigned row = (unsigned)m * 16u + lg * 4u + (unsigned)q;
                        plane_wr_hi(sm, GHI, row, col, s * h1v[m][q]);
                    }
                }
            }
        }
        __syncthreads();  // b2: G(rh) ready

        // prefetch x(t+1): HBM latency hides under cand1 tail + epilogue + gates2
        f32x4 vx[4];
        if (t < 4) stage_load(vx, feat, b0, t + 1, tid);

        // ---- phase 2: cand1 tail (rh part, ks 8..11) + h1 update.
        {
            __builtin_amdgcn_s_setprio(1);
            if (t > 0)
                gemm1nt_2t<4, 256>(sm, GHI, wp1c + (size_t)8 * 2048u, l, accc1);
            __builtin_amdgcn_s_setprio(0);
#pragma unroll
            for (int m = 0; m < 2; ++m) {
                f32x4 c = agg3(Lhi, Llo, accc1[m]);
#pragma unroll
                for (int q = 0; q < 4; ++q) {
                    float cv = fast_tanh(c[q]);
                    float u = u1[m][q];
                    float nh = u * h1v[m][q] + (1.0f - u) * cv;
                    h1v[m][q] = nh;
                    unsigned row = (unsigned)m * 16u + lg * 4u + (unsigned)q;
                    plane_wr_hi(sm, H1HI, row, col, nh);
                }
            }
        }
        __syncthreads();  // b3: h1 updated, X free

        // stage x(t+1) into X plane (X unused until next-t phase 1)
        if (t < 4) stage_store(sm, vx, tid);

        const char* wp2g0 = wsW2G + ((size_t)(w * 8u) * 2048u) + l * 16u;
        const char* wp2g1 = wsW2G + ((size_t)((w + 8u) * 8u) * 2048u) + l * 16u;
        const char* wp2c  = wsW2C + ((size_t)(w * 8u) * 2048u) + l * 16u;

        // ---- phase 3: gates2 (full K) fused with cand2's h1-part (ks 0..3).
        f32x4 accc2[2] = {zf, zf};
        {
            f32x4 acc[2][2] = {{zf, zf}, {zf, zf}};
            __builtin_amdgcn_s_setprio(1);
            gemm_fused<4, 256>(sm, H1HI, wp2g0, wp2g1, wp2c, l, acc, accc2);
            if (t > 0)
                gemm2nt_2t<4, 256>(sm, SHI, wp2g0 + (size_t)4 * 2048u, wp2g1 + (size_t)4 * 2048u, l, acc);
            __builtin_amdgcn_s_setprio(0);
#pragma unroll
            for (int m = 0; m < 2; ++m) {
                f32x4 gr = agg3(Lhi, Llo, acc[m][0]);
                f32x4 gu = agg3(Lhi, Llo, acc[m][1]);
#pragma unroll
                for (int q = 0; q < 4; ++q) {
                    u1[m][q] = fast_sigm(gu[q] + b2u);
                    if (t > 0) {
                        float s = fast_sigm(gr[q] + b2r);
                        unsigned row = (unsigned)m * 16u + lg * 4u + (unsigned)q;
                        plane_wr_hi(sm, GHI, row, col, s * h2v[m][q]);
                    }
                }
            }
        }
        __syncthreads();  // b4: G(rh2) ready

        // ---- phase 4: cand2 tail (rh2 part, ks 4..7) + h2 update.
        {
            __builtin_amdgcn_s_setprio(1);
            if (t > 0)
                gemm1nt_2t<4, 256>(sm, GHI, wp2c + (size_t)4 * 2048u, l, accc2);
            __builtin_amdgcn_s_setprio(0);
#pragma unroll
            for (int m = 0; m < 2; ++m) {
                f32x4 c = agg3(Lhi, Llo, accc2[m]);
#pragma unroll
                for (int q = 0; q < 4; ++q) {
                    float cv = fast_tanh(c[q]);
                    float u = u1[m][q];
                    float nh = u * h2v[m][q] + (1.0f - u) * cv;
                    h2v[m][q] = nh;
                    unsigned row = (unsigned)m * 16u + lg * 4u + (unsigned)q;
                    plane_wr_hi(sm, SHI, row, col, nh);
                }
            }
        }
        __syncthreads();  // b5: h2 updated, X(t+1) staged
    }

    // ---- head: BN -> ReLU -> FC(2048->2) from h2 (S hi plane, bf16)
    {
        int row = tid >> 4, cb = tid & 15;   // 32 rows x 16 col-blocks of 8
        int a = row & 15;
        unsigned sw = ((unsigned)row & 7u) << 4;
        unsigned o0 = (unsigned)row * 256u + (((unsigned)cb * 16u) ^ sw);
        bf8 hA = *(const bf8*)(sm + SHI + o0);
        int k2 = a * 128 + cb * 8;
        float p0 = 0.f, p1 = 0.f;
#pragma unroll
        for (int j = 0; j < 8; ++j) {
            float v = bf2f((unsigned short)hA[j]);
            int k = k2 + j;
            float x = bng[k] * (v - bnm[k]) * rsqrtf(bnv[k] + 1e-5f) + bnb[k];
            x = fmaxf(x, 0.f);
            p0 += x * fcw[2 * k];
            p1 += x * fcw[2 * k + 1];
        }
        p0 += __shfl_down(p0, 8, 16); p0 += __shfl_down(p0, 4, 16);
        p0 += __shfl_down(p0, 2, 16); p0 += __shfl_down(p0, 1, 16);
        p1 += __shfl_down(p1, 8, 16); p1 += __shfl_down(p1, 4, 16);
        p1 += __shfl_down(p1, 2, 16); p1 += __shfl_down(p1, 1, 16);
        if (cb == 0) {
            ((float*)(sm + GHI))[row * 2] = p0;
            ((float*)(sm + GHI))[row * 2 + 1] = p1;
        }
        __syncthreads();
        if (tid < 4) {
            int b = tid >> 1, o = tid & 1;
            float s = fcb[o];
#pragma unroll
            for (int aa = 0; aa < 16; ++aa) s += ((const float*)(sm + GHI))[(b * 16 + aa) * 2 + o];
            out[(size_t)(b0 + b) * 2 + o] = s;
        }
    }
}

extern "C" void kernel_launch(void* const* d_in, const int* in_sizes, int n_in,
                              void* d_out, int out_size, void* d_ws, size_t ws_size,
                              hipStream_t stream) {
    const float* feat = (const float*)d_in[0];
    const float* adj  = (const float*)d_in[1];
    const float* w1g  = (const float*)d_in[2];
    const float* b1g  = (const float*)d_in[3];
    const float* w1c  = (const float*)d_in[4];
    const float* w2g  = (const float*)d_in[5];
    const float* b2g  = (const float*)d_in[6];
    const float* w2c  = (const float*)d_in[7];
    const float* bng  = (const float*)d_in[8];
    const float* bnb  = (const float*)d_in[9];
    const float* bnm  = (const float*)d_in[10];
    const float* bnv  = (const float*)d_in[11];
    const float* fcw  = (const float*)d_in[12];
    const float* fcb  = (const float*)d_in[13];
    float* out = (float*)d_out;
    char* ws = (char*)d_ws;

    int B = in_sizes[0] / (5 * 16 * 256);  // 4096

    hipFuncSetAttribute((const void*)tgcn_main,
                        hipFuncAttributeMaxDynamicSharedMemorySize, LDS_TOTAL);

    tgcn_prep_L<<<1, 256, 0, stream>>>(adj, ws);
    tgcn_prep_W<<<120, 256, 0, stream>>>(w1g, w1c, w2g, w2c, ws);
    tgcn_main<<<B / 2, NTHR, LDS_TOTAL, stream>>>(feat, ws, b1g, b2g,
                                                  bng, bnb, bnm, bnv, fcw, fcb, out);
}

// Round 20
// 399.835 us; speedup vs baseline: 1.2196x; 1.0377x over previous
//
#include <hip/hip_runtime.h>
#include <hip/hip_bf16.h>
#include <math.h>

typedef __attribute__((ext_vector_type(8))) short bf8;
typedef __attribute__((ext_vector_type(4))) short bf4;
typedef __attribute__((ext_vector_type(4))) float f32x4;
typedef __attribute__((ext_vector_type(4))) unsigned short us4;

#define NTHR 512

// ---- LDS layout (bytes), MB=2 (32 rows). bf16 hi-only planes (2-term GEMMs),
// XOR-swizzled byte^=((row&7)<<4). 40 KB -> 2 blocks/CU (register-limited).
#define XHI 0u          // x hi  [32][256], row stride 512B (16 KB)
#define GHI 16384u      // rh hi [32][128], row stride 256B (8 KB)
#define H1HI 24576u     // h1 hi [32][128] (8 KB)
#define SHI 32768u      // h2 hi [32][128] (8 KB)
#define LDS_TOTAL 40960

// ---- workspace layout (bytes)
#define WS_LFRAG 0                      // 2 x 1KB L fragments (hi, lo)
#define WS_W1G   4096                   // 16nt*12ks*2*1024 = 393216
#define WS_W1C   (WS_W1G + 393216)      // 8nt*12ks*2*1024 = 196608
#define WS_W2G   (WS_W1C + 196608)      // 16nt*8ks*2*1024 = 262144
#define WS_W2C   (WS_W2G + 262144)      // 8nt*8ks*2*1024 = 131072

// exact-RNE software conversion (prep kernels only)
__device__ __forceinline__ unsigned short f2bf(float x) {
    unsigned u = __float_as_uint(x);
    unsigned r = (u + 0x7fffu + ((u >> 16) & 1u)) >> 16;
    return (unsigned short)r;
}
// native HW conversion (main kernel hot paths)
__device__ __forceinline__ unsigned short f2bf_n(float x) {
    union { __hip_bfloat16 b; unsigned short u; } t;
    t.b = __float2bfloat16(x);
    return t.u;
}
__device__ __forceinline__ float bf2f(unsigned short h) {
    return __uint_as_float(((unsigned)h) << 16);
}
__device__ __forceinline__ f32x4 mfma16(bf8 a, bf8 b, f32x4 c) {
    return __builtin_amdgcn_mfma_f32_16x16x32_bf16(a, b, c, 0, 0, 0);
}

// Aggregation MFMA: K=16 instruction when available (L-frag zeros k 4-7 anyway).
#if __has_builtin(__builtin_amdgcn_mfma_f32_16x16x16bf16_1k)
#define AGG16 1
typedef bf4 lfrag_t;
__device__ __forceinline__ f32x4 mfma_agg(bf4 a, bf4 b, f32x4 c) {
    return __builtin_amdgcn_mfma_f32_16x16x16bf16_1k(a, b, c, 0, 0, 0);
}
#else
#define AGG16 0
typedef bf8 lfrag_t;
__device__ __forceinline__ f32x4 mfma_agg(bf8 a, bf8 b, f32x4 c) {
    return __builtin_amdgcn_mfma_f32_16x16x32_bf16(a, b, c, 0, 0, 0);
}
#endif

// ---- shared-A addressing (R8-verified XOR fold):
// (ks*64 + lk*16)^sw == [(lk*16)^(sw&48)] + [ks*64 + s6 - 2*s6*(ks&1)], s6=sw&64.

// FUSED segment: gates (2 n-tiles) + cand (1 n-tile) share each A-fragment.
// Per ks per m: 1 ds_read feeds 6 mfma (was 4+2 with a separate cand pass).
template<int KS, int RS>
__device__ __forceinline__ void gemm_fused(const char* sm, unsigned hiO,
                                           const char* wg0, const char* wg1,
                                           const char* wc,
                                           unsigned l, f32x4 (&accg)[2][2],
                                           f32x4 (&accc)[2]) {
    const unsigned lrow = l & 15u, lk = l >> 4;
    const unsigned sw = (lrow & 7u) << 4;
    const unsigned pp = (lk * 16u) ^ (sw & 48u);
    const unsigned s6 = sw & 64u;
    const char* eh = sm + hiO + lrow * (unsigned)RS + pp + s6;
    const char* oh = eh - 2 * (int)s6;
#pragma unroll 2
    for (int ks = 0; ks < KS; ++ks) {
        const char* ph = (ks & 1) ? oh : eh;
        const bf8 bh0 = *(const bf8*)(wg0 + (size_t)ks * 2048u);
        const bf8 bl0 = *(const bf8*)(wg0 + (size_t)ks * 2048u + 1024u);
        const bf8 bh1 = *(const bf8*)(wg1 + (size_t)ks * 2048u);
        const bf8 bl1 = *(const bf8*)(wg1 + (size_t)ks * 2048u + 1024u);
        const bf8 bhc = *(const bf8*)(wc + (size_t)ks * 2048u);
        const bf8 blc = *(const bf8*)(wc + (size_t)ks * 2048u + 1024u);
#pragma unroll
        for (int m = 0; m < 2; ++m) {
            const int off = ks * 64 + m * 16 * RS;
            const bf8 ah = *(const bf8*)(ph + off);
            accg[m][0] = mfma16(ah, bl0, mfma16(ah, bh0, accg[m][0]));
            accg[m][1] = mfma16(ah, bl1, mfma16(ah, bh1, accg[m][1]));
            accc[m]    = mfma16(ah, blc, mfma16(ah, bhc, accc[m]));
        }
    }
}

// gates-only segment, 2 M-tiles x 2 n-tiles (h-operand part):
template<int KS, int RS>
__device__ __forceinline__ void gemm2nt_2t(const char* sm, unsigned hiO,
                                           const char* wp0, const char* wp1,
                                           unsigned l, f32x4 (&acc)[2][2]) {
    const unsigned lrow = l & 15u, lk = l >> 4;
    const unsigned sw = (lrow & 7u) << 4;
    const unsigned pp = (lk * 16u) ^ (sw & 48u);
    const unsigned s6 = sw & 64u;
    const char* eh = sm + hiO + lrow * (unsigned)RS + pp + s6;
    const char* oh = eh - 2 * (int)s6;
#pragma unroll 2
    for (int ks = 0; ks < KS; ++ks) {
        const char* ph = (ks & 1) ? oh : eh;
        const bf8 bh0 = *(const bf8*)(wp0 + (size_t)ks * 2048u);
        const bf8 bl0 = *(const bf8*)(wp0 + (size_t)ks * 2048u + 1024u);
        const bf8 bh1 = *(const bf8*)(wp1 + (size_t)ks * 2048u);
        const bf8 bl1 = *(const bf8*)(wp1 + (size_t)ks * 2048u + 1024u);
#pragma unroll
        for (int m = 0; m < 2; ++m) {
            const int off = ks * 64 + m * 16 * RS;
            const bf8 ah = *(const bf8*)(ph + off);
            acc[m][0] = mfma16(ah, bl0, mfma16(ah, bh0, acc[m][0]));
            acc[m][1] = mfma16(ah, bl1, mfma16(ah, bh1, acc[m][1]));
        }
    }
}

// cand tail segment, 2 M-tiles x 1 n-tile (rh-operand part):
template<int KS, int RS>
__device__ __forceinline__ void gemm1nt_2t(const char* sm, unsigned hiO,
                                           const char* wp, unsigned l, f32x4 (&acc)[2]) {
    const unsigned lrow = l & 15u, lk = l >> 4;
    const unsigned sw = (lrow & 7u) << 4;
    const unsigned pp = (lk * 16u) ^ (sw & 48u);
    const unsigned s6 = sw & 64u;
    const char* eh = sm + hiO + lrow * (unsigned)RS + pp + s6;
    const char* oh = eh - 2 * (int)s6;
#pragma unroll 2
    for (int ks = 0; ks < KS; ++ks) {
        const char* ph = (ks & 1) ? oh : eh;
        const bf8 bh = *(const bf8*)(wp + (size_t)ks * 2048u);
        const bf8 bl = *(const bf8*)(wp + (size_t)ks * 2048u + 1024u);
#pragma unroll
        for (int m = 0; m < 2; ++m) {
            const int off = ks * 64 + m * 16 * RS;
            const bf8 ah = *(const bf8*)(ph + off);
            acc[m] = mfma16(ah, bl, mfma16(ah, bh, acc[m]));
        }
    }
}

// Laplacian aggregation on a C-fragment: D = L @ bf16(pre).
// 2-term with EXACT L (Lhi+Llo) and single-bf16 P: error ~2^-9 on pre-acts,
// same scale as the bf16 activation quantization already in use everywhere.
__device__ __forceinline__ f32x4 agg2(lfrag_t Lhi, lfrag_t Llo, f32x4 p) {
    lfrag_t Bh;
#if !AGG16
    Bh = (bf8){0, 0, 0, 0, 0, 0, 0, 0};
#endif
#pragma unroll
    for (int q = 0; q < 4; ++q) Bh[q] = (short)f2bf_n(p[q]);
    f32x4 d = {0.f, 0.f, 0.f, 0.f};
    d = mfma_agg(Lhi, Bh, d);
    d = mfma_agg(Llo, Bh, d);
    return d;
}

// single-plane (hi) write for the 128-col planes (RS=256), swizzled
__device__ __forceinline__ void plane_wr_hi(char* sm, unsigned hiOff,
                                            unsigned row, unsigned col, float v) {
    unsigned off = row * 256u + ((col * 2u) ^ ((row & 7u) << 4));
    *(unsigned short*)(sm + hiOff + off) = f2bf_n(v);
}

__device__ __forceinline__ float fast_sigm(float x) {
    return __builtin_amdgcn_rcpf(1.0f + __expf(-x));
}
__device__ __forceinline__ float fast_tanh(float x) {
    float e = __expf(2.0f * fminf(x, 40.f));
    return (e - 1.0f) * __builtin_amdgcn_rcpf(e + 1.0f);
}

// feature loads for tile t (32 rows x 256 f32 = 2048 f32x4 / 512 thr = 4/thread)
__device__ __forceinline__ void stage_load(f32x4 (&v)[4], const float* __restrict__ feat,
                                           int b0, int t, int tid) {
#pragma unroll
    for (int p = 0; p < 4; ++p) {
        int e = tid + p * NTHR;
        int row = e >> 6, c4 = (e & 63) << 2;
        size_t gi = (((size_t)(b0 + (row >> 4)) * 5 + t) * 16 + (row & 15)) * 256 + c4;
        v[p] = __builtin_nontemporal_load((const f32x4*)(feat + gi));
    }
}
// hi-only bf16 staging
__device__ __forceinline__ void stage_store(char* sm, const f32x4 (&v)[4], int tid) {
#pragma unroll
    for (int p = 0; p < 4; ++p) {
        int e = tid + p * NTHR;
        int row = e >> 6, c4 = (e & 63) << 2;
        unsigned off = (unsigned)row * 512u + (((unsigned)c4 * 2u) ^ (((unsigned)row & 7u) << 4));
        us4 hi;
#pragma unroll
        for (int q = 0; q < 4; ++q) hi[q] = f2bf_n(v[p][q]);
        *(us4*)(sm + XHI + off) = hi;
    }
}

// ---------------- prep: Laplacian fragments ----------------
__global__ void tgcn_prep_L(const float* __restrict__ adj, char* __restrict__ ws) {
    __shared__ float d[16];
    __shared__ float Lm[16][16];
    int tid = threadIdx.x;
    if (tid < 16) {
        float rs = 1.0f;
        for (int j = 0; j < 16; ++j) rs += adj[tid * 16 + j];
        d[tid] = 1.0f / sqrtf(rs);
    }
    __syncthreads();
    if (tid < 256) {
        int i = tid >> 4, j = tid & 15;
        Lm[i][j] = (adj[j * 16 + i] + (i == j ? 1.0f : 0.0f)) * d[i] * d[j];
    }
    __syncthreads();
    if (tid < 128) {
        int h = tid >> 6, ll = tid & 63;
        int a = ll & 15, g = ll >> 4;
        bf8 f = {0, 0, 0, 0, 0, 0, 0, 0};
        for (int j = 0; j < 4; ++j) {
            float v = Lm[a][4 * g + j];
            unsigned short hi = f2bf(v);
            f[j] = (short)(h == 0 ? hi : f2bf(v - bf2f(hi)));
        }
        *(bf8*)(ws + WS_LFRAG + h * 1024 + ll * 16) = f;
    }
}

// ---------------- prep: weight fragment packing (hi/lo bf16) ----------------
__global__ void tgcn_prep_W(const float* __restrict__ w1g, const float* __restrict__ w1c,
                            const float* __restrict__ w2g, const float* __restrict__ w2c,
                            char* __restrict__ ws) {
    int gid = blockIdx.x * 256 + threadIdx.x;  // 480 frags * 64 lanes = 30720
    if (gid >= 30720) return;
    int fid = gid >> 6, l = gid & 63;
    const float* src; char* dst; int NK, N, nt, ks;
    if (fid < 192)      { src = w1g; dst = ws + WS_W1G; NK = 12; N = 256; nt = fid / 12; ks = fid % 12; }
    else if (fid < 288) { int f = fid - 192; src = w1c; dst = ws + WS_W1C; NK = 12; N = 128; nt = f / 12; ks = f % 12; }
    else if (fid < 416) { int f = fid - 288; src = w2g; dst = ws + WS_W2G; NK = 8;  N = 256; nt = f / 8;  ks = f % 8; }
    else                { int f = fid - 416; src = w2c; dst = ws + WS_W2C; NK = 8;  N = 128; nt = f / 8;  ks = f % 8; }
    int col = nt * 16 + (l & 15);
    int kbase = ks * 32 + (l >> 4) * 8;
    bf8 hi, lo;
#pragma unroll
    for (int j = 0; j < 8; ++j) {
        float v = src[(size_t)(kbase + j) * N + col];
        unsigned short h = f2bf(v);
        hi[j] = (short)h;
        lo[j] = (short)f2bf(v - bf2f(h));
    }
    char* base = dst + ((size_t)(nt * NK + ks) * 2048) + l * 16;
    *(bf8*)(base) = hi;
    *(bf8*)(base + 1024) = lo;
}

// ---------------- main fused kernel ----------------
// MB=2: 512 threads (8 waves), 32 rows, 40 KB LDS, waves_per_eu(4,4) -> 2 blocks/CU.
// R19 structure (fused shared-A GEMMs, 414.9 us) + agg2: 2-term aggregation with
// exact L and bf16 pre-acts (error scale identical to existing bf16 activation
// quantization). Cuts 1 MFMA + ~12 VALU per agg call (12 calls/wave/t).
__global__ __launch_bounds__(NTHR)
__attribute__((amdgpu_waves_per_eu(4, 4)))
void tgcn_main(
    const float* __restrict__ feat, const char* __restrict__ ws,
    const float* __restrict__ b1g, const float* __restrict__ b2g,
    const float* __restrict__ bng, const float* __restrict__ bnb,
    const float* __restrict__ bnm, const float* __restrict__ bnv,
    const float* __restrict__ fcw, const float* __restrict__ fcb,
    float* __restrict__ out) {
    extern __shared__ char sm[];
    const int tid = threadIdx.x;
    const int b0 = blockIdx.x * 2;
    const unsigned l = (unsigned)tid & 63u;
    const unsigned w = __builtin_amdgcn_readfirstlane((unsigned)tid >> 6);  // wave 0..7
    const unsigned lrow = l & 15u, lg = l >> 4;

    const lfrag_t Lhi = *(const lfrag_t*)(ws + WS_LFRAG + l * 16u);
    const lfrag_t Llo = *(const lfrag_t*)(ws + WS_LFRAG + 1024u + l * 16u);

    const float b1r = b1g[w * 16u + lrow];
    const float b1u = b1g[128u + w * 16u + lrow];
    const float b2r = b2g[w * 16u + lrow];
    const float b2u = b2g[128u + w * 16u + lrow];
    const unsigned col = w * 16u + lrow;   // this wave's H-column

    {
        f32x4 v[4];
        stage_load(v, feat, b0, 0, tid);
        stage_store(sm, v, tid);
    }
    __syncthreads();  // b1: X(0) ready (h planes never read at t=0)

    const char* wsW1G = ws + WS_W1G;
    const char* wsW1C = ws + WS_W1C;
    const char* wsW2G = ws + WS_W2G;
    const char* wsW2C = ws + WS_W2C;
    const f32x4 zf = {0.f, 0.f, 0.f, 0.f};

    float u1[2][4];                 // this wave's u-gate fragment [m][q]
    float h1v[2][4], h2v[2][4];     // register-resident h1/h2 column slice (fp32)
#pragma unroll
    for (int m = 0; m < 2; ++m)
#pragma unroll
        for (int q = 0; q < 4; ++q) { h1v[m][q] = 0.f; h2v[m][q] = 0.f; }

    for (int t = 0; t < 5; ++t) {
        const char* wp1g0 = wsW1G + ((size_t)(w * 12u) * 2048u) + l * 16u;
        const char* wp1g1 = wsW1G + ((size_t)((w + 8u) * 12u) * 2048u) + l * 16u;
        const char* wp1c  = wsW1C + ((size_t)(w * 12u) * 2048u) + l * 16u;

        // ---- phase 1: gates1 (full K) fused with cand1's X-part (ks 0..7).
        f32x4 accc1[2] = {zf, zf};
        {
            f32x4 acc[2][2] = {{zf, zf}, {zf, zf}};
            __builtin_amdgcn_s_setprio(1);
            gemm_fused<8, 512>(sm, XHI, wp1g0, wp1g1, wp1c, l, acc, accc1);
            if (t > 0)
                gemm2nt_2t<4, 256>(sm, H1HI, wp1g0 + (size_t)8 * 2048u, wp1g1 + (size_t)8 * 2048u, l, acc);
            __builtin_amdgcn_s_setprio(0);
#pragma unroll
            for (int m = 0; m < 2; ++m) {
                f32x4 gu = agg2(Lhi, Llo, acc[m][1]);
#pragma unroll
                for (int q = 0; q < 4; ++q) u1[m][q] = fast_sigm(gu[q] + b1u);
                if (t > 0) {
                    f32x4 gr = agg2(Lhi, Llo, acc[m][0]);
#pragma unroll
                    for (int q = 0; q < 4; ++q) {
                        float s = fast_sigm(gr[q] + b1r);
                        unsigned row = (unsigned)m * 16u + lg * 4u + (unsigned)q;
                        plane_wr_hi(sm, GHI, row, col, s * h1v[m][q]);
                    }
                }
            }
        }
        __syncthreads();  // b2: G(rh) ready

        // prefetch x(t+1): HBM latency hides under cand1 tail + epilogue + gates2
        f32x4 vx[4];
        if (t < 4) stage_load(vx, feat, b0, t + 1, tid);

        // ---- phase 2: cand1 tail (rh part, ks 8..11) + h1 update.
        {
            __builtin_amdgcn_s_setprio(1);
            if (t > 0)
                gemm1nt_2t<4, 256>(sm, GHI, wp1c + (size_t)8 * 2048u, l, accc1);
            __builtin_amdgcn_s_setprio(0);
#pragma unroll
            for (int m = 0; m < 2; ++m) {
                f32x4 c = agg2(Lhi, Llo, accc1[m]);
#pragma unroll
                for (int q = 0; q < 4; ++q) {
                    float cv = fast_tanh(c[q]);
                    float u = u1[m][q];
                    float nh = u * h1v[m][q] + (1.0f - u) * cv;
                    h1v[m][q] = nh;
                    unsigned row = (unsigned)m * 16u + lg * 4u + (unsigned)q;
                    plane_wr_hi(sm, H1HI, row, col, nh);
                }
            }
        }
        __syncthreads();  // b3: h1 updated, X free

        // stage x(t+1) into X plane (X unused until next-t phase 1)
        if (t < 4) stage_store(sm, vx, tid);

        const char* wp2g0 = wsW2G + ((size_t)(w * 8u) * 2048u) + l * 16u;
        const char* wp2g1 = wsW2G + ((size_t)((w + 8u) * 8u) * 2048u) + l * 16u;
        const char* wp2c  = wsW2C + ((size_t)(w * 8u) * 2048u) + l * 16u;

        // ---- phase 3: gates2 (full K) fused with cand2's h1-part (ks 0..3).
        f32x4 accc2[2] = {zf, zf};
        {
            f32x4 acc[2][2] = {{zf, zf}, {zf, zf}};
            __builtin_amdgcn_s_setprio(1);
            gemm_fused<4, 256>(sm, H1HI, wp2g0, wp2g1, wp2c, l, acc, accc2);
            if (t > 0)
                gemm2nt_2t<4, 256>(sm, SHI, wp2g0 + (size_t)4 * 2048u, wp2g1 + (size_t)4 * 2048u, l, acc);
            __builtin_amdgcn_s_setprio(0);
#pragma unroll
            for (int m = 0; m < 2; ++m) {
                f32x4 gu = agg2(Lhi, Llo, acc[m][1]);
#pragma unroll
                for (int q = 0; q < 4; ++q) u1[m][q] = fast_sigm(gu[q] + b2u);
                if (t > 0) {
                    f32x4 gr = agg2(Lhi, Llo, acc[m][0]);
#pragma unroll
                    for (int q = 0; q < 4; ++q) {
                        float s = fast_sigm(gr[q] + b2r);
                        unsigned row = (unsigned)m * 16u + lg * 4u + (unsigned)q;
                        plane_wr_hi(sm, GHI, row, col, s * h2v[m][q]);
                    }
                }
            }
        }
        __syncthreads();  // b4: G(rh2) ready

        // ---- phase 4: cand2 tail (rh2 part, ks 4..7) + h2 update.
        {
            __builtin_amdgcn_s_setprio(1);
            if (t > 0)
                gemm1nt_2t<4, 256>(sm, GHI, wp2c + (size_t)4 * 2048u, l, accc2);
            __builtin_amdgcn_s_setprio(0);
#pragma unroll
            for (int m = 0; m < 2; ++m) {
                f32x4 c = agg2(Lhi, Llo, accc2[m]);
#pragma unroll
                for (int q = 0; q < 4; ++q) {
                    float cv = fast_tanh(c[q]);
                    float u = u1[m][q];
                    float nh = u * h2v[m][q] + (1.0f - u) * cv;
                    h2v[m][q] = nh;
                    unsigned row = (unsigned)m * 16u + lg * 4u + (unsigned)q;
                    plane_wr_hi(sm, SHI, row, col, nh);
                }
            }
        }
        __syncthreads();  // b5: h2 updated, X(t+1) staged
    }

    // ---- head: BN -> ReLU -> FC(2048->2) from h2 (S hi plane, bf16)
    {
        int row = tid >> 4, cb = tid & 15;   // 32 rows x 16 col-blocks of 8
        int a = row & 15;
        unsigned sw = ((unsigned)row & 7u) << 4;
        unsigned o0 = (unsigned)row * 256u + (((unsigned)cb * 16u) ^ sw);
        bf8 hA = *(const bf8*)(sm + SHI + o0);
        int k2 = a * 128 + cb * 8;
        float p0 = 0.f, p1 = 0.f;
#pragma unroll
        for (int j = 0; j < 8; ++j) {
            float v = bf2f((unsigned short)hA[j]);
            int k = k2 + j;
            float x = bng[k] * (v - bnm[k]) * rsqrtf(bnv[k] + 1e-5f) + bnb[k];
            x = fmaxf(x, 0.f);
            p0 += x * fcw[2 * k];
            p1 += x * fcw[2 * k + 1];
        }
        p0 += __shfl_down(p0, 8, 16); p0 += __shfl_down(p0, 4, 16);
        p0 += __shfl_down(p0, 2, 16); p0 += __shfl_down(p0, 1, 16);
        p1 += __shfl_down(p1, 8, 16); p1 += __shfl_down(p1, 4, 16);
        p1 += __shfl_down(p1, 2, 16); p1 += __shfl_down(p1, 1, 16);
        if (cb == 0) {
            ((float*)(sm + GHI))[row * 2] = p0;
            ((float*)(sm + GHI))[row * 2 + 1] = p1;
        }
        __syncthreads();
        if (tid < 4) {
            int b = tid >> 1, o = tid & 1;
            float s = fcb[o];
#pragma unroll
            for (int aa = 0; aa < 16; ++aa) s += ((const float*)(sm + GHI))[(b * 16 + aa) * 2 + o];
            out[(size_t)(b0 + b) * 2 + o] = s;
        }
    }
}

extern "C" void kernel_launch(void* const* d_in, const int* in_sizes, int n_in,
                              void* d_out, int out_size, void* d_ws, size_t ws_size,
                              hipStream_t stream) {
    const float* feat = (const float*)d_in[0];
    const float* adj  = (const float*)d_in[1];
    const float* w1g  = (const float*)d_in[2];
    const float* b1g  = (const float*)d_in[3];
    const float* w1c  = (const float*)d_in[4];
    const float* w2g  = (const float*)d_in[5];
    const float* b2g  = (const float*)d_in[6];
    const float* w2c  = (const float*)d_in[7];
    const float* bng  = (const float*)d_in[8];
    const float* bnb  = (const float*)d_in[9];
    const float* bnm  = (const float*)d_in[10];
    const float* bnv  = (const float*)d_in[11];
    const float* fcw  = (const float*)d_in[12];
    const float* fcb  = (const float*)d_in[13];
    float* out = (float*)d_out;
    char* ws = (char*)d_ws;

    int B = in_sizes[0] / (5 * 16 * 256);  // 4096

    hipFuncSetAttribute((const void*)tgcn_main,
                        hipFuncAttributeMaxDynamicSharedMemorySize, LDS_TOTAL);

    tgcn_prep_L<<<1, 256, 0, stream>>>(adj, ws);
    tgcn_prep_W<<<120, 256, 0, stream>>>(w1g, w1c, w2g, w2c, ws);
    tgcn_main<<<B / 2, NTHR, LDS_TOTAL, stream>>>(feat, ws, b1g, b2g,
                                                  bng, bnb, bnm, bnv, fcw, fcb, out);
}

// Round 21
// 261.319 us; speedup vs baseline: 1.8660x; 1.5301x over previous
//
#include <hip/hip_runtime.h>
#include <hip/hip_bf16.h>
#include <math.h>

typedef __attribute__((ext_vector_type(8))) short bf8;
typedef __attribute__((ext_vector_type(4))) short bf4;
typedef __attribute__((ext_vector_type(4))) float f32x4;
typedef __attribute__((ext_vector_type(4))) unsigned short us4;

#define NTHR 512

// ---- LDS layout (bytes), MB=2 (32 rows). bf16 hi-only planes, XOR-swizzled
// byte^=((row&7)<<4). 40 KB -> 2 blocks/CU (register-limited).
#define XHI 0u          // x hi  [32][256], row stride 512B (16 KB)
#define GHI 16384u      // rh hi [32][128], row stride 256B (8 KB)
#define H1HI 24576u     // h1 hi [32][128] (8 KB)
#define SHI 32768u      // h2 hi [32][128] (8 KB)
#define LDS_TOTAL 40960

// ---- workspace layout (bytes)
#define WS_LFRAG 0                      // 2 x 1KB L fragments (hi, lo)
#define WS_W1G   4096                   // 16nt*12ks*2*1024 = 393216
#define WS_W1C   (WS_W1G + 393216)      // 8nt*12ks*2*1024 = 196608
#define WS_W2G   (WS_W1C + 196608)      // 16nt*8ks*2*1024 = 262144
#define WS_W2C   (WS_W2G + 262144)      // 8nt*8ks*2*1024 = 131072

// exact-RNE software conversion (prep kernels only)
__device__ __forceinline__ unsigned short f2bf(float x) {
    unsigned u = __float_as_uint(x);
    unsigned r = (u + 0x7fffu + ((u >> 16) & 1u)) >> 16;
    return (unsigned short)r;
}
// native HW conversion (main kernel hot paths)
__device__ __forceinline__ unsigned short f2bf_n(float x) {
    union { __hip_bfloat16 b; unsigned short u; } t;
    t.b = __float2bfloat16(x);
    return t.u;
}
__device__ __forceinline__ float bf2f(unsigned short h) {
    return __uint_as_float(((unsigned)h) << 16);
}
__device__ __forceinline__ f32x4 mfma16(bf8 a, bf8 b, f32x4 c) {
    return __builtin_amdgcn_mfma_f32_16x16x32_bf16(a, b, c, 0, 0, 0);
}

// Aggregation MFMA: K=16 instruction when available (L-frag zeros k 4-7 anyway).
#if __has_builtin(__builtin_amdgcn_mfma_f32_16x16x16bf16_1k)
#define AGG16 1
typedef bf4 lfrag_t;
__device__ __forceinline__ f32x4 mfma_agg(bf4 a, bf4 b, f32x4 c) {
    return __builtin_amdgcn_mfma_f32_16x16x16bf16_1k(a, b, c, 0, 0, 0);
}
#else
#define AGG16 0
typedef bf8 lfrag_t;
__device__ __forceinline__ f32x4 mfma_agg(bf8 a, bf8 b, f32x4 c) {
    return __builtin_amdgcn_mfma_f32_16x16x32_bf16(a, b, c, 0, 0, 0);
}
#endif

// ---- shared-A addressing (R8-verified XOR fold):
// (ks*64 + lk*16)^sw == [(lk*16)^(sw&48)] + [ks*64 + s6 - 2*s6*(ks&1)], s6=sw&64.
// R21: weights single-bf16 (lo fragments unread) -> 1 mfma per (ks,m,n-tile).

// FUSED segment: gates (2 n-tiles) + cand (1 n-tile) share each A-fragment.
template<int KS, int RS>
__device__ __forceinline__ void gemm_fused(const char* sm, unsigned hiO,
                                           const char* wg0, const char* wg1,
                                           const char* wc,
                                           unsigned l, f32x4 (&accg)[2][2],
                                           f32x4 (&accc)[2]) {
    const unsigned lrow = l & 15u, lk = l >> 4;
    const unsigned sw = (lrow & 7u) << 4;
    const unsigned pp = (lk * 16u) ^ (sw & 48u);
    const unsigned s6 = sw & 64u;
    const char* eh = sm + hiO + lrow * (unsigned)RS + pp + s6;
    const char* oh = eh - 2 * (int)s6;
#pragma unroll 2
    for (int ks = 0; ks < KS; ++ks) {
        const char* ph = (ks & 1) ? oh : eh;
        const bf8 bh0 = *(const bf8*)(wg0 + (size_t)ks * 2048u);
        const bf8 bh1 = *(const bf8*)(wg1 + (size_t)ks * 2048u);
        const bf8 bhc = *(const bf8*)(wc + (size_t)ks * 2048u);
#pragma unroll
        for (int m = 0; m < 2; ++m) {
            const int off = ks * 64 + m * 16 * RS;
            const bf8 ah = *(const bf8*)(ph + off);
            accg[m][0] = mfma16(ah, bh0, accg[m][0]);
            accg[m][1] = mfma16(ah, bh1, accg[m][1]);
            accc[m]    = mfma16(ah, bhc, accc[m]);
        }
    }
}

// gates-only segment, 2 M-tiles x 2 n-tiles (h-operand part):
template<int KS, int RS>
__device__ __forceinline__ void gemm2nt_1t(const char* sm, unsigned hiO,
                                           const char* wp0, const char* wp1,
                                           unsigned l, f32x4 (&acc)[2][2]) {
    const unsigned lrow = l & 15u, lk = l >> 4;
    const unsigned sw = (lrow & 7u) << 4;
    const unsigned pp = (lk * 16u) ^ (sw & 48u);
    const unsigned s6 = sw & 64u;
    const char* eh = sm + hiO + lrow * (unsigned)RS + pp + s6;
    const char* oh = eh - 2 * (int)s6;
#pragma unroll 2
    for (int ks = 0; ks < KS; ++ks) {
        const char* ph = (ks & 1) ? oh : eh;
        const bf8 bh0 = *(const bf8*)(wp0 + (size_t)ks * 2048u);
        const bf8 bh1 = *(const bf8*)(wp1 + (size_t)ks * 2048u);
#pragma unroll
        for (int m = 0; m < 2; ++m) {
            const int off = ks * 64 + m * 16 * RS;
            const bf8 ah = *(const bf8*)(ph + off);
            acc[m][0] = mfma16(ah, bh0, acc[m][0]);
            acc[m][1] = mfma16(ah, bh1, acc[m][1]);
        }
    }
}

// cand tail segment, 2 M-tiles x 1 n-tile (rh-operand part):
template<int KS, int RS>
__device__ __forceinline__ void gemm1nt_1t(const char* sm, unsigned hiO,
                                           const char* wp, unsigned l, f32x4 (&acc)[2]) {
    const unsigned lrow = l & 15u, lk = l >> 4;
    const unsigned sw = (lrow & 7u) << 4;
    const unsigned pp = (lk * 16u) ^ (sw & 48u);
    const unsigned s6 = sw & 64u;
    const char* eh = sm + hiO + lrow * (unsigned)RS + pp + s6;
    const char* oh = eh - 2 * (int)s6;
#pragma unroll 2
    for (int ks = 0; ks < KS; ++ks) {
        const char* ph = (ks & 1) ? oh : eh;
        const bf8 bh = *(const bf8*)(wp + (size_t)ks * 2048u);
#pragma unroll
        for (int m = 0; m < 2; ++m) {
            const int off = ks * 64 + m * 16 * RS;
            const bf8 ah = *(const bf8*)(ph + off);
            acc[m] = mfma16(ah, bh, acc[m]);
        }
    }
}

// Laplacian aggregation on a C-fragment: D = L @ bf16(pre).
// Exact L (Lhi+Llo), bf16 P: error ~2^-9 on pre-acts (invisible at output).
__device__ __forceinline__ f32x4 agg2(lfrag_t Lhi, lfrag_t Llo, f32x4 p) {
    lfrag_t Bh;
#if !AGG16
    Bh = (bf8){0, 0, 0, 0, 0, 0, 0, 0};
#endif
#pragma unroll
    for (int q = 0; q < 4; ++q) Bh[q] = (short)f2bf_n(p[q]);
    f32x4 d = {0.f, 0.f, 0.f, 0.f};
    d = mfma_agg(Lhi, Bh, d);
    d = mfma_agg(Llo, Bh, d);
    return d;
}

// single-plane (hi) write for the 128-col planes (RS=256), swizzled
__device__ __forceinline__ void plane_wr_hi(char* sm, unsigned hiOff,
                                            unsigned row, unsigned col, float v) {
    unsigned off = row * 256u + ((col * 2u) ^ ((row & 7u) << 4));
    *(unsigned short*)(sm + hiOff + off) = f2bf_n(v);
}

__device__ __forceinline__ float fast_sigm(float x) {
    return __builtin_amdgcn_rcpf(1.0f + __expf(-x));
}
__device__ __forceinline__ float fast_tanh(float x) {
    float e = __expf(2.0f * fminf(x, 40.f));
    return (e - 1.0f) * __builtin_amdgcn_rcpf(e + 1.0f);
}

// feature loads for tile t (32 rows x 256 f32 = 2048 f32x4 / 512 thr = 4/thread)
__device__ __forceinline__ void stage_load(f32x4 (&v)[4], const float* __restrict__ feat,
                                           int b0, int t, int tid) {
#pragma unroll
    for (int p = 0; p < 4; ++p) {
        int e = tid + p * NTHR;
        int row = e >> 6, c4 = (e & 63) << 2;
        size_t gi = (((size_t)(b0 + (row >> 4)) * 5 + t) * 16 + (row & 15)) * 256 + c4;
        v[p] = __builtin_nontemporal_load((const f32x4*)(feat + gi));
    }
}
// hi-only bf16 staging
__device__ __forceinline__ void stage_store(char* sm, const f32x4 (&v)[4], int tid) {
#pragma unroll
    for (int p = 0; p < 4; ++p) {
        int e = tid + p * NTHR;
        int row = e >> 6, c4 = (e & 63) << 2;
        unsigned off = (unsigned)row * 512u + (((unsigned)c4 * 2u) ^ (((unsigned)row & 7u) << 4));
        us4 hi;
#pragma unroll
        for (int q = 0; q < 4; ++q) hi[q] = f2bf_n(v[p][q]);
        *(us4*)(sm + XHI + off) = hi;
    }
}

// ---------------- prep: Laplacian fragments ----------------
__global__ void tgcn_prep_L(const float* __restrict__ adj, char* __restrict__ ws) {
    __shared__ float d[16];
    __shared__ float Lm[16][16];
    int tid = threadIdx.x;
    if (tid < 16) {
        float rs = 1.0f;
        for (int j = 0; j < 16; ++j) rs += adj[tid * 16 + j];
        d[tid] = 1.0f / sqrtf(rs);
    }
    __syncthreads();
    if (tid < 256) {
        int i = tid >> 4, j = tid & 15;
        Lm[i][j] = (adj[j * 16 + i] + (i == j ? 1.0f : 0.0f)) * d[i] * d[j];
    }
    __syncthreads();
    if (tid < 128) {
        int h = tid >> 6, ll = tid & 63;
        int a = ll & 15, g = ll >> 4;
        bf8 f = {0, 0, 0, 0, 0, 0, 0, 0};
        for (int j = 0; j < 4; ++j) {
            float v = Lm[a][4 * g + j];
            unsigned short hi = f2bf(v);
            f[j] = (short)(h == 0 ? hi : f2bf(v - bf2f(hi)));
        }
        *(bf8*)(ws + WS_LFRAG + h * 1024 + ll * 16) = f;
    }
}

// ---------------- prep: weight fragment packing (hi/lo bf16) ----------------
// (lo fragments still written; main kernel reads hi only since R21)
__global__ void tgcn_prep_W(const float* __restrict__ w1g, const float* __restrict__ w1c,
                            const float* __restrict__ w2g, const float* __restrict__ w2c,
                            char* __restrict__ ws) {
    int gid = blockIdx.x * 256 + threadIdx.x;  // 480 frags * 64 lanes = 30720
    if (gid >= 30720) return;
    int fid = gid >> 6, l = gid & 63;
    const float* src; char* dst; int NK, N, nt, ks;
    if (fid < 192)      { src = w1g; dst = ws + WS_W1G; NK = 12; N = 256; nt = fid / 12; ks = fid % 12; }
    else if (fid < 288) { int f = fid - 192; src = w1c; dst = ws + WS_W1C; NK = 12; N = 128; nt = f / 12; ks = f % 12; }
    else if (fid < 416) { int f = fid - 288; src = w2g; dst = ws + WS_W2G; NK = 8;  N = 256; nt = f / 8;  ks = f % 8; }
    else                { int f = fid - 416; src = w2c; dst = ws + WS_W2C; NK = 8;  N = 128; nt = f / 8;  ks = f % 8; }
    int col = nt * 16 + (l & 15);
    int kbase = ks * 32 + (l >> 4) * 8;
    bf8 hi, lo;
#pragma unroll
    for (int j = 0; j < 8; ++j) {
        float v = src[(size_t)(kbase + j) * N + col];
        unsigned short h = f2bf(v);
        hi[j] = (short)h;
        lo[j] = (short)f2bf(v - bf2f(h));
    }
    char* base = dst + ((size_t)(nt * NK + ks) * 2048) + l * 16;
    *(bf8*)(base) = hi;
    *(bf8*)(base + 1024) = lo;
}

// ---------------- main fused kernel ----------------
// MB=2: 512 threads (8 waves), 32 rows, 40 KB LDS, waves_per_eu(4,4) -> 2 blocks/CU.
// R20 structure (fused shared-A GEMMs + agg2, 399.8 us) with single-bf16 weights:
// halves all GEMM MFMAs and B-loads. Weight-quant error ~2^-9 relative, the same
// scale as activation/agg quantization already measured invisible at the output.
__global__ __launch_bounds__(NTHR)
__attribute__((amdgpu_waves_per_eu(4, 4)))
void tgcn_main(
    const float* __restrict__ feat, const char* __restrict__ ws,
    const float* __restrict__ b1g, const float* __restrict__ b2g,
    const float* __restrict__ bng, const float* __restrict__ bnb,
    const float* __restrict__ bnm, const float* __restrict__ bnv,
    const float* __restrict__ fcw, const float* __restrict__ fcb,
    float* __restrict__ out) {
    extern __shared__ char sm[];
    const int tid = threadIdx.x;
    const int b0 = blockIdx.x * 2;
    const unsigned l = (unsigned)tid & 63u;
    const unsigned w = __builtin_amdgcn_readfirstlane((unsigned)tid >> 6);  // wave 0..7
    const unsigned lrow = l & 15u, lg = l >> 4;

    const lfrag_t Lhi = *(const lfrag_t*)(ws + WS_LFRAG + l * 16u);
    const lfrag_t Llo = *(const lfrag_t*)(ws + WS_LFRAG + 1024u + l * 16u);

    const float b1r = b1g[w * 16u + lrow];
    const float b1u = b1g[128u + w * 16u + lrow];
    const float b2r = b2g[w * 16u + lrow];
    const float b2u = b2g[128u + w * 16u + lrow];
    const unsigned col = w * 16u + lrow;   // this wave's H-column

    {
        f32x4 v[4];
        stage_load(v, feat, b0, 0, tid);
        stage_store(sm, v, tid);
    }
    __syncthreads();  // b1: X(0) ready (h planes never read at t=0)

    const char* wsW1G = ws + WS_W1G;
    const char* wsW1C = ws + WS_W1C;
    const char* wsW2G = ws + WS_W2G;
    const char* wsW2C = ws + WS_W2C;
    const f32x4 zf = {0.f, 0.f, 0.f, 0.f};

    float u1[2][4];                 // this wave's u-gate fragment [m][q]
    float h1v[2][4], h2v[2][4];     // register-resident h1/h2 column slice (fp32)
#pragma unroll
    for (int m = 0; m < 2; ++m)
#pragma unroll
        for (int q = 0; q < 4; ++q) { h1v[m][q] = 0.f; h2v[m][q] = 0.f; }

    for (int t = 0; t < 5; ++t) {
        const char* wp1g0 = wsW1G + ((size_t)(w * 12u) * 2048u) + l * 16u;
        const char* wp1g1 = wsW1G + ((size_t)((w + 8u) * 12u) * 2048u) + l * 16u;
        const char* wp1c  = wsW1C + ((size_t)(w * 12u) * 2048u) + l * 16u;

        // ---- phase 1: gates1 (full K) fused with cand1's X-part (ks 0..7).
        f32x4 accc1[2] = {zf, zf};
        {
            f32x4 acc[2][2] = {{zf, zf}, {zf, zf}};
            __builtin_amdgcn_s_setprio(1);
            gemm_fused<8, 512>(sm, XHI, wp1g0, wp1g1, wp1c, l, acc, accc1);
            if (t > 0)
                gemm2nt_1t<4, 256>(sm, H1HI, wp1g0 + (size_t)8 * 2048u, wp1g1 + (size_t)8 * 2048u, l, acc);
            __builtin_amdgcn_s_setprio(0);
#pragma unroll
            for (int m = 0; m < 2; ++m) {
                f32x4 gu = agg2(Lhi, Llo, acc[m][1]);
#pragma unroll
                for (int q = 0; q < 4; ++q) u1[m][q] = fast_sigm(gu[q] + b1u);
                if (t > 0) {
                    f32x4 gr = agg2(Lhi, Llo, acc[m][0]);
#pragma unroll
                    for (int q = 0; q < 4; ++q) {
                        float s = fast_sigm(gr[q] + b1r);
                        unsigned row = (unsigned)m * 16u + lg * 4u + (unsigned)q;
                        plane_wr_hi(sm, GHI, row, col, s * h1v[m][q]);
                    }
                }
            }
        }
        __syncthreads();  // b2: G(rh) ready

        // prefetch x(t+1): HBM latency hides under cand1 tail + epilogue + gates2
        f32x4 vx[4];
        if (t < 4) stage_load(vx, feat, b0, t + 1, tid);

        // ---- phase 2: cand1 tail (rh part, ks 8..11) + h1 update.
        {
            __builtin_amdgcn_s_setprio(1);
            if (t > 0)
                gemm1nt_1t<4, 256>(sm, GHI, wp1c + (size_t)8 * 2048u, l, accc1);
            __builtin_amdgcn_s_setprio(0);
#pragma unroll
            for (int m = 0; m < 2; ++m) {
                f32x4 c = agg2(Lhi, Llo, accc1[m]);
#pragma unroll
                for (int q = 0; q < 4; ++q) {
                    float cv = fast_tanh(c[q]);
                    float u = u1[m][q];
                    float nh = u * h1v[m][q] + (1.0f - u) * cv;
                    h1v[m][q] = nh;
                    unsigned row = (unsigned)m * 16u + lg * 4u + (unsigned)q;
                    plane_wr_hi(sm, H1HI, row, col, nh);
                }
            }
        }
        __syncthreads();  // b3: h1 updated, X free

        // stage x(t+1) into X plane (X unused until next-t phase 1)
        if (t < 4) stage_store(sm, vx, tid);

        const char* wp2g0 = wsW2G + ((size_t)(w * 8u) * 2048u) + l * 16u;
        const char* wp2g1 = wsW2G + ((size_t)((w + 8u) * 8u) * 2048u) + l * 16u;
        const char* wp2c  = wsW2C + ((size_t)(w * 8u) * 2048u) + l * 16u;

        // ---- phase 3: gates2 (full K) fused with cand2's h1-part (ks 0..3).
        f32x4 accc2[2] = {zf, zf};
        {
            f32x4 acc[2][2] = {{zf, zf}, {zf, zf}};
            __builtin_amdgcn_s_setprio(1);
            gemm_fused<4, 256>(sm, H1HI, wp2g0, wp2g1, wp2c, l, acc, accc2);
            if (t > 0)
                gemm2nt_1t<4, 256>(sm, SHI, wp2g0 + (size_t)4 * 2048u, wp2g1 + (size_t)4 * 2048u, l, acc);
            __builtin_amdgcn_s_setprio(0);
#pragma unroll
            for (int m = 0; m < 2; ++m) {
                f32x4 gu = agg2(Lhi, Llo, acc[m][1]);
#pragma unroll
                for (int q = 0; q < 4; ++q) u1[m][q] = fast_sigm(gu[q] + b2u);
                if (t > 0) {
                    f32x4 gr = agg2(Lhi, Llo, acc[m][0]);
#pragma unroll
                    for (int q = 0; q < 4; ++q) {
                        float s = fast_sigm(gr[q] + b2r);
                        unsigned row = (unsigned)m * 16u + lg * 4u + (unsigned)q;
                        plane_wr_hi(sm, GHI, row, col, s * h2v[m][q]);
                    }
                }
            }
        }
        __syncthreads();  // b4: G(rh2) ready

        // ---- phase 4: cand2 tail (rh2 part, ks 4..7) + h2 update.
        {
            __builtin_amdgcn_s_setprio(1);
            if (t > 0)
                gemm1nt_1t<4, 256>(sm, GHI, wp2c + (size_t)4 * 2048u, l, accc2);
            __builtin_amdgcn_s_setprio(0);
#pragma unroll
            for (int m = 0; m < 2; ++m) {
                f32x4 c = agg2(Lhi, Llo, accc2[m]);
#pragma unroll
                for (int q = 0; q < 4; ++q) {
                    float cv = fast_tanh(c[q]);
                    float u = u1[m][q];
                    float nh = u * h2v[m][q] + (1.0f - u) * cv;
                    h2v[m][q] = nh;
                    unsigned row = (unsigned)m * 16u + lg * 4u + (unsigned)q;
                    plane_wr_hi(sm, SHI, row, col, nh);
                }
            }
        }
        __syncthreads();  // b5: h2 updated, X(t+1) staged
    }

    // ---- head: BN -> ReLU -> FC(2048->2) from h2 (S hi plane, bf16)
    {
        int row = tid >> 4, cb = tid & 15;   // 32 rows x 16 col-blocks of 8
        int a = row & 15;
        unsigned sw = ((unsigned)row & 7u) << 4;
        unsigned o0 = (unsigned)row * 256u + (((unsigned)cb * 16u) ^ sw);
        bf8 hA = *(const bf8*)(sm + SHI + o0);
        int k2 = a * 128 + cb * 8;
        float p0 = 0.f, p1 = 0.f;
#pragma unroll
        for (int j = 0; j < 8; ++j) {
            float v = bf2f((unsigned short)hA[j]);
            int k = k2 + j;
            float x = bng[k] * (v - bnm[k]) * rsqrtf(bnv[k] + 1e-5f) + bnb[k];
            x = fmaxf(x, 0.f);
            p0 += x * fcw[2 * k];
            p1 += x * fcw[2 * k + 1];
        }
        p0 += __shfl_down(p0, 8, 16); p0 += __shfl_down(p0, 4, 16);
        p0 += __shfl_down(p0, 2, 16); p0 += __shfl_down(p0, 1, 16);
        p1 += __shfl_down(p1, 8, 16); p1 += __shfl_down(p1, 4, 16);
        p1 += __shfl_down(p1, 2, 16); p1 += __shfl_down(p1, 1, 16);
        if (cb == 0) {
            ((float*)(sm + GHI))[row * 2] = p0;
            ((float*)(sm + GHI))[row * 2 + 1] = p1;
        }
        __syncthreads();
        if (tid < 4) {
            int b = tid >> 1, o = tid & 1;
            float s = fcb[o];
#pragma unroll
            for (int aa = 0; aa < 16; ++aa) s += ((const float*)(sm + GHI))[(b * 16 + aa) * 2 + o];
            out[(size_t)(b0 + b) * 2 + o] = s;
        }
    }
}

extern "C" void kernel_launch(void* const* d_in, const int* in_sizes, int n_in,
                              void* d_out, int out_size, void* d_ws, size_t ws_size,
                              hipStream_t stream) {
    const float* feat = (const float*)d_in[0];
    const float* adj  = (const float*)d_in[1];
    const float* w1g  = (const float*)d_in[2];
    const float* b1g  = (const float*)d_in[3];
    const float* w1c  = (const float*)d_in[4];
    const float* w2g  = (const float*)d_in[5];
    const float* b2g  = (const float*)d_in[6];
    const float* w2c  = (const float*)d_in[7];
    const float* bng  = (const float*)d_in[8];
    const float* bnb  = (const float*)d_in[9];
    const float* bnm  = (const float*)d_in[10];
    const float* bnv  = (const float*)d_in[11];
    const float* fcw  = (const float*)d_in[12];
    const float* fcb  = (const float*)d_in[13];
    float* out = (float*)d_out;
    char* ws = (char*)d_ws;

    int B = in_sizes[0] / (5 * 16 * 256);  // 4096

    hipFuncSetAttribute((const void*)tgcn_main,
                        hipFuncAttributeMaxDynamicSharedMemorySize, LDS_TOTAL);

    tgcn_prep_L<<<1, 256, 0, stream>>>(adj, ws);
    tgcn_prep_W<<<120, 256, 0, stream>>>(w1g, w1c, w2g, w2c, ws);
    tgcn_main<<<B / 2, NTHR, LDS_TOTAL, stream>>>(feat, ws, b1g, b2g,
                                                  bng, bnb, bnm, bnv, fcw, fcb, out);
}